// Round 4
// baseline (612.197 us; speedup 1.0000x reference)
//
#include <hip/hip_runtime.h>

#define V_   3
#define N_   200000
#define D_   128
#define B_   32768
#define K_   10
#define TOT_ 65536

constexpr int BLOCKS_PER_SLICE = 2048;
constexpr int SLICES           = 6;
// 16 groups/block (4 waves x 4 groups of 16 lanes), 1 row per group per term.

// Slice -> fused terms {type,i,j}. Slices 0-2: negs+ctx from neigh_W[s].
// Slices 3-5: negs+ctx from node_W[s-3]. Node slices have 2 terms (3rd = pad).
__device__ const int TS[SLICES][3][3] = {
    {{0,0,0},{2,1,0},{2,2,0}},
    {{0,1,1},{2,0,1},{2,2,1}},
    {{0,2,2},{2,0,2},{2,1,2}},
    {{1,1,0},{1,2,0},{1,1,0}},
    {{1,0,1},{1,2,1},{1,0,1}},
    {{1,0,2},{1,1,2},{1,0,2}},
};

template <int CTRL>
__device__ __forceinline__ float dpp_add(float v) {
    int x = __builtin_amdgcn_update_dpp(0, __float_as_int(v), CTRL, 0xF, 0xF, true);
    return v + __int_as_float(x);
}

// 16-lane sum on the VALU pipe: quad xor1, xor2, then row_ror:4 + row_ror:8.
__device__ __forceinline__ float grp_sum16(float v) {
    v = dpp_add<0xB1>(v);
    v = dpp_add<0x4E>(v);
    v = dpp_add<0x124>(v);
    v = dpp_add<0x128>(v);
    return v;
}

__device__ __forceinline__ float dot8(float4 a0, float4 a1, float4 b0, float4 b1) {
    float s = a0.x * b0.x;
    s = fmaf(a0.y, b0.y, s);
    s = fmaf(a0.z, b0.z, s);
    s = fmaf(a0.w, b0.w, s);
    s = fmaf(a1.x, b1.x, s);
    s = fmaf(a1.y, b1.y, s);
    s = fmaf(a1.z, b1.z, s);
    s = fmaf(a1.w, b1.w, s);
    return s;
}

__device__ __forceinline__ float log_sigmoid(float x) {
    float ax = fabsf(x);
    return fminf(x, 0.f) - __logf(1.f + __expf(-ax));
}

__global__ __launch_bounds__(256) void sgns_kernel(
    const int*   __restrict__ countp,
    const int*   __restrict__ shuffle,
    const int*   __restrict__ nodes_idx,
    const int*   __restrict__ neigh_idx,
    const int*   __restrict__ neg1,
    const int*   __restrict__ neg2,
    const int*   __restrict__ neg3,
    const float* __restrict__ node_W,
    const float* __restrict__ neigh_W,
    float*       __restrict__ acc)
{
    const int slice = blockIdx.x >> 11;          // /2048
    const int blk   = blockIdx.x & 2047;
    const int wave  = threadIdx.x >> 6;
    const int lane  = threadIdx.x & 63;
    const int grp   = lane >> 4;
    const int lw    = lane & 15;
    const int grpid = wave * 4 + grp;            // 0..15
    const int b     = blk * 16 + grpid;          // row 0..32767
    const int count = countp[0];
    const int nt    = (slice < 3) ? 3 : 2;

    auto eval = [&](int type, int i, int j) -> float {
        const int sh = shuffle[i * TOT_ + count + b];
        const int ns = nodes_idx[i * TOT_ + sh];

        const float* crow = node_W + ((size_t)i * N_ + ns) * (size_t)D_;
        float4 c0 = *(const float4*)(crow + lw * 4);
        float4 c1 = *(const float4*)(crow + 64 + lw * 4);

        const float* xrow;
        const float* negTable;
        const int*   negBase;
        if (type == 0) {
            int gs = neigh_idx[i * TOT_ + sh];
            xrow     = neigh_W + ((size_t)i * N_ + gs) * (size_t)D_;
            negTable = neigh_W + (size_t)i * N_ * D_;
            negBase  = neg1 + (size_t)i * B_ * K_;
        } else if (type == 1) {
            xrow     = node_W + ((size_t)j * N_ + ns) * (size_t)D_;
            negTable = node_W + (size_t)j * N_ * D_;
            negBase  = neg2 + (size_t)(j * V_ + i) * B_ * K_;
        } else {
            int gs = neigh_idx[i * TOT_ + sh];
            xrow     = neigh_W + ((size_t)j * N_ + gs) * (size_t)D_;
            negTable = neigh_W + (size_t)j * N_ * D_;
            negBase  = neg3 + (size_t)(j * V_ + i) * B_ * K_;
        }
        float4 x0 = *(const float4*)(xrow + lw * 4);
        float4 x1 = *(const float4*)(xrow + 64 + lw * 4);

        int myidx = (lw < K_) ? negBase[(size_t)b * K_ + lw] : 0;

        float rowacc = log_sigmoid(grp_sum16(dot8(c0, c1, x0, x1)));
#pragma unroll
        for (int k = 0; k < K_; ++k) {
            int nk = __shfl(myidx, (lane & 48) | k, 64);
            const float* nrow = negTable + (size_t)nk * (size_t)D_;
            float4 n0 = *(const float4*)(nrow + lw * 4);
            float4 n1 = *(const float4*)(nrow + 64 + lw * 4);
            rowacc += log_sigmoid(-grp_sum16(dot8(c0, c1, n0, n1)));
        }
        return rowacc;   // identical across the 16 lanes of this group
    };

    float wt0 = eval(TS[slice][0][0], TS[slice][0][1], TS[slice][0][2]);
    float wt1 = eval(TS[slice][1][0], TS[slice][1][1], TS[slice][1][2]);
    float wt2 = (nt == 3) ? eval(TS[slice][2][0], TS[slice][2][1], TS[slice][2][2]) : 0.f;

    // fold the 4 groups of the wave
    wt0 += __shfl_xor(wt0, 16, 64); wt0 += __shfl_xor(wt0, 32, 64);
    wt1 += __shfl_xor(wt1, 16, 64); wt1 += __shfl_xor(wt1, 32, 64);
    wt2 += __shfl_xor(wt2, 16, 64); wt2 += __shfl_xor(wt2, 32, 64);

    __shared__ float part[4][3];
    if (lane == 0) { part[wave][0] = wt0; part[wave][1] = wt1; part[wave][2] = wt2; }
    __syncthreads();
    if (threadIdx.x == 0) {
        float s0 = part[0][0] + part[1][0] + part[2][0] + part[3][0];
        float s1 = part[0][1] + part[1][1] + part[2][1] + part[3][1];
        float s2 = part[0][2] + part[1][2] + part[2][2] + part[3][2];
        atomicAdd(&acc[TS[slice][0][0]], s0);
        atomicAdd(&acc[TS[slice][1][0]], s1);
        if (nt == 3) atomicAdd(&acc[TS[slice][2][0]], s2);
    }
}

__global__ void finalize_kernel(const float* __restrict__ acc,
                                const float* __restrict__ hyp1,
                                const float* __restrict__ hyp2,
                                float* __restrict__ out)
{
    const float invB = 1.0f / (float)B_;
    float s1 = acc[0], s2 = acc[1], s3 = acc[2];
    out[0] = -(s1 * (invB / 9.0f) + hyp1[0] * s2 * (invB / 18.0f) + hyp2[0] * s3 * (invB / 18.0f));
}

extern "C" void kernel_launch(void* const* d_in, const int* in_sizes, int n_in,
                              void* d_out, int out_size, void* d_ws, size_t ws_size,
                              hipStream_t stream)
{
    const int*   countp    = (const int*)d_in[0];
    const int*   shuffle   = (const int*)d_in[1];
    const int*   nodes_idx = (const int*)d_in[2];
    const int*   neigh_idx = (const int*)d_in[3];
    const int*   neg1      = (const int*)d_in[4];
    const int*   neg2      = (const int*)d_in[5];
    const int*   neg3      = (const int*)d_in[6];
    const float* node_W    = (const float*)d_in[7];
    const float* neigh_W   = (const float*)d_in[8];
    const float* hyp1      = (const float*)d_in[9];
    const float* hyp2      = (const float*)d_in[10];

    float* acc = (float*)d_ws;
    hipMemsetAsync(acc, 0, 3 * sizeof(float), stream);

    dim3 grid(SLICES * BLOCKS_PER_SLICE);
    dim3 block(256);
    sgns_kernel<<<grid, block, 0, stream>>>(countp, shuffle, nodes_idx, neigh_idx,
                                            neg1, neg2, neg3, node_W, neigh_W, acc);

    finalize_kernel<<<1, 1, 0, stream>>>(acc, hyp1, hyp2, (float*)d_out);
}

// Round 5
// 399.400 us; speedup vs baseline: 1.5328x; 1.5328x over previous
//
#include <hip/hip_runtime.h>

#define V_   3
#define N_   200000
#define D_   128
#define B_   32768
#define K_   10
#define TOT_ 65536

constexpr int BLOCKS_PER_TERM = 512;
constexpr int ROWS_PER_BLOCK  = B_ / BLOCKS_PER_TERM;             // 64
constexpr int WAVES_PER_BLOCK = 4;                                // 256 threads
constexpr int ROWS_PER_WAVE   = ROWS_PER_BLOCK / WAVES_PER_BLOCK; // 16
constexpr int GROUPS_PER_WAVE = 4;                                // 16 lanes/row
constexpr int ITERS           = ROWS_PER_WAVE / GROUPS_PER_WAVE;  // 4

constexpr size_t TBL_ELEMS      = (size_t)V_ * N_ * D_;   // 76.8e6 per table
constexpr size_t BF16_TBL_BYTES = TBL_ELEMS * 2;          // 153.6 MB per table
constexpr size_t ACC_BYTES      = 256;
constexpr size_t WS_NEED        = ACC_BYTES + 2 * BF16_TBL_BYTES;

// Term schedule grouped by negative-sample table slice (round-3 TMAP).
__device__ const int TMAP[15][3] = {
    {0, 0, 0}, {2, 1, 0}, {2, 2, 0},
    {0, 1, 1}, {2, 0, 1}, {2, 2, 1},
    {0, 2, 2}, {2, 0, 2}, {2, 1, 2},
    {1, 1, 0}, {1, 2, 0},
    {1, 0, 1}, {1, 2, 1},
    {1, 0, 2}, {1, 1, 2},
};

template <int CTRL>
__device__ __forceinline__ float dpp_add(float v) {
    int x = __builtin_amdgcn_update_dpp(0, __float_as_int(v), CTRL, 0xF, 0xF, true);
    return v + __int_as_float(x);
}

// 16-lane sum on the VALU pipe.
__device__ __forceinline__ float grp_sum16(float v) {
    v = dpp_add<0xB1>(v);
    v = dpp_add<0x4E>(v);
    v = dpp_add<0x124>(v);
    v = dpp_add<0x128>(v);
    return v;
}

__device__ __forceinline__ float log_sigmoid(float x) {
    float ax = fabsf(x);
    return fminf(x, 0.f) - __logf(1.f + __expf(-ax));
}

// ---------------- bf16 helpers ----------------
__device__ __forceinline__ unsigned bfr(unsigned u) {           // f32->bf16 RNE
    return (u + 0x7FFFu + ((u >> 16) & 1u)) >> 16;
}
__device__ __forceinline__ unsigned pack2(float lo, float hi) {
    return bfr(__float_as_uint(lo)) | (bfr(__float_as_uint(hi)) << 16);
}
__device__ __forceinline__ float blo(unsigned u) { return __uint_as_float(u << 16); }
__device__ __forceinline__ float bhi(unsigned u) { return __uint_as_float(u & 0xFFFF0000u); }

__device__ __forceinline__ float dot8bf(uint4 a, uint4 b) {
    float s = blo(a.x) * blo(b.x);
    s = fmaf(bhi(a.x), bhi(b.x), s);
    s = fmaf(blo(a.y), blo(b.y), s);
    s = fmaf(bhi(a.y), bhi(b.y), s);
    s = fmaf(blo(a.z), blo(b.z), s);
    s = fmaf(bhi(a.z), bhi(b.z), s);
    s = fmaf(blo(a.w), blo(b.w), s);
    s = fmaf(bhi(a.w), bhi(b.w), s);
    return s;
}

__global__ __launch_bounds__(256) void cvt_kernel(const float4* __restrict__ src,
                                                  uint4* __restrict__ dst, int n8)
{
    const int stride = gridDim.x * blockDim.x;
    for (int g = blockIdx.x * blockDim.x + threadIdx.x; g < n8; g += stride) {
        float4 a = src[2 * g];
        float4 b = src[2 * g + 1];
        uint4 o;
        o.x = pack2(a.x, a.y);
        o.y = pack2(a.z, a.w);
        o.z = pack2(b.x, b.y);
        o.w = pack2(b.z, b.w);
        dst[g] = o;
    }
}

// ---------------- bf16 gather kernel (round-3 structure) ----------------
__global__ __launch_bounds__(256) void sgns_bf16(
    const int*   __restrict__ countp,
    const int*   __restrict__ shuffle,
    const int*   __restrict__ nodes_idx,
    const int*   __restrict__ neigh_idx,
    const int*   __restrict__ neg1,
    const int*   __restrict__ neg2,
    const int*   __restrict__ neg3,
    const uint4* __restrict__ nodeT,     // bf16, 16 uint4 per row
    const uint4* __restrict__ neighT,
    float*       __restrict__ acc)
{
    const int slot = blockIdx.x / BLOCKS_PER_TERM;
    const int blk  = blockIdx.x % BLOCKS_PER_TERM;
    const int wave = threadIdx.x >> 6;
    const int lane = threadIdx.x & 63;
    const int grp  = lane >> 4;
    const int lw   = lane & 15;
    const int count = countp[0];

    const int type = TMAP[slot][0];
    const int i    = TMAP[slot][1];
    const int j    = TMAP[slot][2];

    const int*   negBase;
    const uint4* negTable;
    if (type == 0)      { negTable = neighT + (size_t)i * N_ * 16; negBase = neg1 + (size_t)i * B_ * K_; }
    else if (type == 1) { negTable = nodeT  + (size_t)j * N_ * 16; negBase = neg2 + (size_t)(j * V_ + i) * B_ * K_; }
    else                { negTable = neighT + (size_t)j * N_ * 16; negBase = neg3 + (size_t)(j * V_ + i) * B_ * K_; }

    float wsum = 0.f;
    const int rowbase = blk * ROWS_PER_BLOCK + wave * ROWS_PER_WAVE;

    for (int r = 0; r < ITERS; ++r) {
        const int b  = rowbase + r * GROUPS_PER_WAVE + grp;
        const int sh = shuffle[i * TOT_ + count + b];
        const int ns = nodes_idx[i * TOT_ + sh];

        uint4 c = nodeT[((size_t)i * N_ + ns) * 16 + lw];

        const uint4* xrow;
        if (type == 0) {
            int gs = neigh_idx[i * TOT_ + sh];
            xrow = neighT + ((size_t)i * N_ + gs) * 16;
        } else if (type == 1) {
            xrow = nodeT + ((size_t)j * N_ + ns) * 16;
        } else {
            int gs = neigh_idx[i * TOT_ + sh];
            xrow = neighT + ((size_t)j * N_ + gs) * 16;
        }
        uint4 x = xrow[lw];

        int myidx = (lw < K_) ? negBase[(size_t)b * K_ + lw] : 0;

        float rowacc = log_sigmoid(grp_sum16(dot8bf(c, x)));
#pragma unroll
        for (int k = 0; k < K_; ++k) {
            int nk = __shfl(myidx, (lane & 48) | k, 64);
            uint4 n = negTable[(size_t)nk * 16 + lw];
            rowacc += log_sigmoid(-grp_sum16(dot8bf(c, n)));
        }
        wsum += rowacc;
    }

    wsum += __shfl_xor(wsum, 16, 64);
    wsum += __shfl_xor(wsum, 32, 64);

    __shared__ float part[WAVES_PER_BLOCK];
    if (lane == 0) part[wave] = wsum;
    __syncthreads();
    if (threadIdx.x == 0) {
        float s = part[0] + part[1] + part[2] + part[3];
        atomicAdd(&acc[type], s);
    }
}

// ---------------- f32 fallback (proven round-3 kernel) ----------------
__device__ __forceinline__ float dot8(float4 a0, float4 a1, float4 b0, float4 b1) {
    float s = a0.x * b0.x;
    s = fmaf(a0.y, b0.y, s);
    s = fmaf(a0.z, b0.z, s);
    s = fmaf(a0.w, b0.w, s);
    s = fmaf(a1.x, b1.x, s);
    s = fmaf(a1.y, b1.y, s);
    s = fmaf(a1.z, b1.z, s);
    s = fmaf(a1.w, b1.w, s);
    return s;
}

__global__ __launch_bounds__(256) void sgns_f32(
    const int*   __restrict__ countp,
    const int*   __restrict__ shuffle,
    const int*   __restrict__ nodes_idx,
    const int*   __restrict__ neigh_idx,
    const int*   __restrict__ neg1,
    const int*   __restrict__ neg2,
    const int*   __restrict__ neg3,
    const float* __restrict__ node_W,
    const float* __restrict__ neigh_W,
    float*       __restrict__ acc)
{
    const int slot = blockIdx.x / BLOCKS_PER_TERM;
    const int blk  = blockIdx.x % BLOCKS_PER_TERM;
    const int wave = threadIdx.x >> 6;
    const int lane = threadIdx.x & 63;
    const int grp  = lane >> 4;
    const int lw   = lane & 15;
    const int count = countp[0];

    const int type = TMAP[slot][0];
    const int i    = TMAP[slot][1];
    const int j    = TMAP[slot][2];

    const int*   negBase;
    const float* negTable;
    if (type == 0)      { negTable = neigh_W + (size_t)i * N_ * D_; negBase = neg1 + (size_t)i * B_ * K_; }
    else if (type == 1) { negTable = node_W  + (size_t)j * N_ * D_; negBase = neg2 + (size_t)(j * V_ + i) * B_ * K_; }
    else                { negTable = neigh_W + (size_t)j * N_ * D_; negBase = neg3 + (size_t)(j * V_ + i) * B_ * K_; }

    float wsum = 0.f;
    const int rowbase = blk * ROWS_PER_BLOCK + wave * ROWS_PER_WAVE;

    for (int r = 0; r < ITERS; ++r) {
        const int b  = rowbase + r * GROUPS_PER_WAVE + grp;
        const int sh = shuffle[i * TOT_ + count + b];
        const int ns = nodes_idx[i * TOT_ + sh];

        const float* crow = node_W + ((size_t)i * N_ + ns) * (size_t)D_;
        float4 c0 = *(const float4*)(crow + lw * 4);
        float4 c1 = *(const float4*)(crow + 64 + lw * 4);

        const float* xrow;
        if (type == 0) {
            int gs = neigh_idx[i * TOT_ + sh];
            xrow = neigh_W + ((size_t)i * N_ + gs) * (size_t)D_;
        } else if (type == 1) {
            xrow = node_W + ((size_t)j * N_ + ns) * (size_t)D_;
        } else {
            int gs = neigh_idx[i * TOT_ + sh];
            xrow = neigh_W + ((size_t)j * N_ + gs) * (size_t)D_;
        }
        float4 x0 = *(const float4*)(xrow + lw * 4);
        float4 x1 = *(const float4*)(xrow + 64 + lw * 4);

        int myidx = (lw < K_) ? negBase[(size_t)b * K_ + lw] : 0;

        float rowacc = log_sigmoid(grp_sum16(dot8(c0, c1, x0, x1)));
#pragma unroll
        for (int k = 0; k < K_; ++k) {
            int nk = __shfl(myidx, (lane & 48) | k, 64);
            const float* nrow = negTable + (size_t)nk * (size_t)D_;
            float4 n0 = *(const float4*)(nrow + lw * 4);
            float4 n1 = *(const float4*)(nrow + 64 + lw * 4);
            rowacc += log_sigmoid(-grp_sum16(dot8(c0, c1, n0, n1)));
        }
        wsum += rowacc;
    }

    wsum += __shfl_xor(wsum, 16, 64);
    wsum += __shfl_xor(wsum, 32, 64);

    __shared__ float part[WAVES_PER_BLOCK];
    if (lane == 0) part[wave] = wsum;
    __syncthreads();
    if (threadIdx.x == 0) {
        float s = part[0] + part[1] + part[2] + part[3];
        atomicAdd(&acc[type], s);
    }
}

__global__ void finalize_kernel(const float* __restrict__ acc,
                                const float* __restrict__ hyp1,
                                const float* __restrict__ hyp2,
                                float* __restrict__ out)
{
    const float invB = 1.0f / (float)B_;
    float s1 = acc[0], s2 = acc[1], s3 = acc[2];
    out[0] = -(s1 * (invB / 9.0f) + hyp1[0] * s2 * (invB / 18.0f) + hyp2[0] * s3 * (invB / 18.0f));
}

extern "C" void kernel_launch(void* const* d_in, const int* in_sizes, int n_in,
                              void* d_out, int out_size, void* d_ws, size_t ws_size,
                              hipStream_t stream)
{
    const int*   countp    = (const int*)d_in[0];
    const int*   shuffle   = (const int*)d_in[1];
    const int*   nodes_idx = (const int*)d_in[2];
    const int*   neigh_idx = (const int*)d_in[3];
    const int*   neg1      = (const int*)d_in[4];
    const int*   neg2      = (const int*)d_in[5];
    const int*   neg3      = (const int*)d_in[6];
    const float* node_W    = (const float*)d_in[7];
    const float* neigh_W   = (const float*)d_in[8];
    const float* hyp1      = (const float*)d_in[9];
    const float* hyp2      = (const float*)d_in[10];

    float* acc = (float*)d_ws;
    hipMemsetAsync(acc, 0, 3 * sizeof(float), stream);

    dim3 block(256);

    if (ws_size >= WS_NEED) {
        uint4* nodeT  = (uint4*)((char*)d_ws + ACC_BYTES);
        uint4* neighT = (uint4*)((char*)d_ws + ACC_BYTES + BF16_TBL_BYTES);
        const int n8 = (int)(TBL_ELEMS / 8);                 // 9.6M groups per table
        cvt_kernel<<<4096, block, 0, stream>>>((const float4*)node_W,  nodeT,  n8);
        cvt_kernel<<<4096, block, 0, stream>>>((const float4*)neigh_W, neighT, n8);
        sgns_bf16<<<dim3(15 * BLOCKS_PER_TERM), block, 0, stream>>>(
            countp, shuffle, nodes_idx, neigh_idx, neg1, neg2, neg3,
            (const uint4*)nodeT, (const uint4*)neighT, acc);
    } else {
        sgns_f32<<<dim3(15 * BLOCKS_PER_TERM), block, 0, stream>>>(
            countp, shuffle, nodes_idx, neigh_idx, neg1, neg2, neg3,
            node_W, neigh_W, acc);
    }

    finalize_kernel<<<1, 1, 0, stream>>>(acc, hyp1, hyp2, (float*)d_out);
}

// Round 7
// 299.719 us; speedup vs baseline: 2.0426x; 1.3326x over previous
//
#include <hip/hip_runtime.h>

#define V_   3
#define N_   200000
#define D_   128
#define B_   32768
#define K_   10
#define TOT_ 65536

constexpr int BLOCKS_PER_TERM = 512;
constexpr int ROWS_PER_BLOCK  = B_ / BLOCKS_PER_TERM;             // 64
constexpr int WAVES_PER_BLOCK = 4;                                // 256 threads
constexpr int ROWS_PER_WAVE   = ROWS_PER_BLOCK / WAVES_PER_BLOCK; // 16
constexpr int GROUPS_PER_WAVE = 4;                                // 16 lanes/row
constexpr int ITERS           = ROWS_PER_WAVE / GROUPS_PER_WAVE;  // 4

constexpr size_t TBL_ELEMS     = (size_t)V_ * N_ * D_;    // 76.8e6 per table
constexpr size_t FP8_TBL_BYTES = TBL_ELEMS;               // 76.8 MB per table
constexpr size_t ACC_BYTES     = 256;
constexpr size_t WS_NEED       = ACC_BYTES + 2 * FP8_TBL_BYTES;

// Term schedule grouped by negative-sample table slice (round-3 TMAP).
__device__ const int TMAP[15][3] = {
    {0, 0, 0}, {2, 1, 0}, {2, 2, 0},
    {0, 1, 1}, {2, 0, 1}, {2, 2, 1},
    {0, 2, 2}, {2, 0, 2}, {2, 1, 2},
    {1, 1, 0}, {1, 2, 0},
    {1, 0, 1}, {1, 2, 1},
    {1, 0, 2}, {1, 1, 2},
};

typedef float v2f __attribute__((ext_vector_type(2)));

template <int CTRL>
__device__ __forceinline__ float dpp_add(float v) {
    int x = __builtin_amdgcn_update_dpp(0, __float_as_int(v), CTRL, 0xF, 0xF, true);
    return v + __int_as_float(x);
}

// 16-lane sum on the VALU pipe.
__device__ __forceinline__ float grp_sum16(float v) {
    v = dpp_add<0xB1>(v);
    v = dpp_add<0x4E>(v);
    v = dpp_add<0x124>(v);
    v = dpp_add<0x128>(v);
    return v;
}

__device__ __forceinline__ float log_sigmoid(float x) {
    float ax = fabsf(x);
    return fminf(x, 0.f) - __logf(1.f + __expf(-ax));
}

// ---------------- fp8 e4m3 helpers (HW cvt; selectors must be constants) ----------------
__device__ __forceinline__ unsigned cvt4_fp8(float a, float b, float c, float d) {
    int v = __builtin_amdgcn_cvt_pk_fp8_f32(a, b, 0, false);   // low word
    v = __builtin_amdgcn_cvt_pk_fp8_f32(c, d, v, true);        // high word
    return (unsigned)v;
}
template <bool HI>
__device__ __forceinline__ v2f upk2(unsigned v) {
    return __builtin_amdgcn_cvt_pk_f32_fp8((int)v, HI);
}

__global__ __launch_bounds__(256) void cvt_fp8(const float4* __restrict__ src,
                                               uint2* __restrict__ dst, int n8)
{
    const int stride = gridDim.x * blockDim.x;
    for (int g = blockIdx.x * blockDim.x + threadIdx.x; g < n8; g += stride) {
        float4 a = src[2 * g];
        float4 b = src[2 * g + 1];
        uint2 o;
        o.x = cvt4_fp8(a.x, a.y, a.z, a.w);
        o.y = cvt4_fp8(b.x, b.y, b.z, b.w);
        dst[g] = o;
    }
}

// dot of this lane's 8 fp8 elements of n against pre-decoded c (8 floats)
__device__ __forceinline__ float dot8f8(v2f c0, v2f c1, v2f c2, v2f c3, uint2 n) {
    v2f n0 = upk2<false>(n.x), n1 = upk2<true>(n.x);
    v2f n2 = upk2<false>(n.y), n3 = upk2<true>(n.y);
    float s = c0.x * n0.x;
    s = fmaf(c0.y, n0.y, s);
    s = fmaf(c1.x, n1.x, s);
    s = fmaf(c1.y, n1.y, s);
    s = fmaf(c2.x, n2.x, s);
    s = fmaf(c2.y, n2.y, s);
    s = fmaf(c3.x, n3.x, s);
    s = fmaf(c3.y, n3.y, s);
    return s;
}

// ---------------- fp8 gather kernel (round-3 structure) ----------------
// Tables: 16 uint2 per row (128 fp8). Lane lw loads uint2 -> 8 elements.
__global__ __launch_bounds__(256) void sgns_fp8(
    const int*   __restrict__ countp,
    const int*   __restrict__ shuffle,
    const int*   __restrict__ nodes_idx,
    const int*   __restrict__ neigh_idx,
    const int*   __restrict__ neg1,
    const int*   __restrict__ neg2,
    const int*   __restrict__ neg3,
    const uint2* __restrict__ nodeT,
    const uint2* __restrict__ neighT,
    float*       __restrict__ acc)
{
    const int slot = blockIdx.x / BLOCKS_PER_TERM;
    const int blk  = blockIdx.x % BLOCKS_PER_TERM;
    const int wave = threadIdx.x >> 6;
    const int lane = threadIdx.x & 63;
    const int grp  = lane >> 4;
    const int lw   = lane & 15;
    const int count = countp[0];

    const int type = TMAP[slot][0];
    const int i    = TMAP[slot][1];
    const int j    = TMAP[slot][2];

    const int*   negBase;
    const uint2* negTable;
    if (type == 0)      { negTable = neighT + (size_t)i * N_ * 16; negBase = neg1 + (size_t)i * B_ * K_; }
    else if (type == 1) { negTable = nodeT  + (size_t)j * N_ * 16; negBase = neg2 + (size_t)(j * V_ + i) * B_ * K_; }
    else                { negTable = neighT + (size_t)j * N_ * 16; negBase = neg3 + (size_t)(j * V_ + i) * B_ * K_; }

    float wsum = 0.f;
    const int rowbase = blk * ROWS_PER_BLOCK + wave * ROWS_PER_WAVE;

    for (int r = 0; r < ITERS; ++r) {
        const int b  = rowbase + r * GROUPS_PER_WAVE + grp;
        const int sh = shuffle[i * TOT_ + count + b];
        const int ns = nodes_idx[i * TOT_ + sh];

        uint2 c8 = nodeT[((size_t)i * N_ + ns) * 16 + lw];
        v2f c0 = upk2<false>(c8.x), c1 = upk2<true>(c8.x);
        v2f c2 = upk2<false>(c8.y), c3 = upk2<true>(c8.y);

        const uint2* xrow;
        if (type == 0) {
            int gs = neigh_idx[i * TOT_ + sh];
            xrow = neighT + ((size_t)i * N_ + gs) * 16;
        } else if (type == 1) {
            xrow = nodeT + ((size_t)j * N_ + ns) * 16;
        } else {
            int gs = neigh_idx[i * TOT_ + sh];
            xrow = neighT + ((size_t)j * N_ + gs) * 16;
        }
        uint2 x8 = xrow[lw];

        int myidx = (lw < K_) ? negBase[(size_t)b * K_ + lw] : 0;

        float rowacc = log_sigmoid(grp_sum16(dot8f8(c0, c1, c2, c3, x8)));
#pragma unroll
        for (int k = 0; k < K_; ++k) {
            int nk = __shfl(myidx, (lane & 48) | k, 64);
            uint2 n8v = negTable[(size_t)nk * 16 + lw];
            rowacc += log_sigmoid(-grp_sum16(dot8f8(c0, c1, c2, c3, n8v)));
        }
        wsum += rowacc;
    }

    wsum += __shfl_xor(wsum, 16, 64);
    wsum += __shfl_xor(wsum, 32, 64);

    __shared__ float part[WAVES_PER_BLOCK];
    if (lane == 0) part[wave] = wsum;
    __syncthreads();
    if (threadIdx.x == 0) {
        float s = part[0] + part[1] + part[2] + part[3];
        atomicAdd(&acc[type], s);
    }
}

// ---------------- f32 fallback (proven round-3 kernel) ----------------
__device__ __forceinline__ float dot8(float4 a0, float4 a1, float4 b0, float4 b1) {
    float s = a0.x * b0.x;
    s = fmaf(a0.y, b0.y, s);
    s = fmaf(a0.z, b0.z, s);
    s = fmaf(a0.w, b0.w, s);
    s = fmaf(a1.x, b1.x, s);
    s = fmaf(a1.y, b1.y, s);
    s = fmaf(a1.z, b1.z, s);
    s = fmaf(a1.w, b1.w, s);
    return s;
}

__global__ __launch_bounds__(256) void sgns_f32(
    const int*   __restrict__ countp,
    const int*   __restrict__ shuffle,
    const int*   __restrict__ nodes_idx,
    const int*   __restrict__ neigh_idx,
    const int*   __restrict__ neg1,
    const int*   __restrict__ neg2,
    const int*   __restrict__ neg3,
    const float* __restrict__ node_W,
    const float* __restrict__ neigh_W,
    float*       __restrict__ acc)
{
    const int slot = blockIdx.x / BLOCKS_PER_TERM;
    const int blk  = blockIdx.x % BLOCKS_PER_TERM;
    const int wave = threadIdx.x >> 6;
    const int lane = threadIdx.x & 63;
    const int grp  = lane >> 4;
    const int lw   = lane & 15;
    const int count = countp[0];

    const int type = TMAP[slot][0];
    const int i    = TMAP[slot][1];
    const int j    = TMAP[slot][2];

    const int*   negBase;
    const float* negTable;
    if (type == 0)      { negTable = neigh_W + (size_t)i * N_ * D_; negBase = neg1 + (size_t)i * B_ * K_; }
    else if (type == 1) { negTable = node_W  + (size_t)j * N_ * D_; negBase = neg2 + (size_t)(j * V_ + i) * B_ * K_; }
    else                { negTable = neigh_W + (size_t)j * N_ * D_; negBase = neg3 + (size_t)(j * V_ + i) * B_ * K_; }

    float wsum = 0.f;
    const int rowbase = blk * ROWS_PER_BLOCK + wave * ROWS_PER_WAVE;

    for (int r = 0; r < ITERS; ++r) {
        const int b  = rowbase + r * GROUPS_PER_WAVE + grp;
        const int sh = shuffle[i * TOT_ + count + b];
        const int ns = nodes_idx[i * TOT_ + sh];

        const float* crow = node_W + ((size_t)i * N_ + ns) * (size_t)D_;
        float4 c0 = *(const float4*)(crow + lw * 4);
        float4 c1 = *(const float4*)(crow + 64 + lw * 4);

        const float* xrow;
        if (type == 0) {
            int gs = neigh_idx[i * TOT_ + sh];
            xrow = neigh_W + ((size_t)i * N_ + gs) * (size_t)D_;
        } else if (type == 1) {
            xrow = node_W + ((size_t)j * N_ + ns) * (size_t)D_;
        } else {
            int gs = neigh_idx[i * TOT_ + sh];
            xrow = neigh_W + ((size_t)j * N_ + gs) * (size_t)D_;
        }
        float4 x0 = *(const float4*)(xrow + lw * 4);
        float4 x1 = *(const float4*)(xrow + 64 + lw * 4);

        int myidx = (lw < K_) ? negBase[(size_t)b * K_ + lw] : 0;

        float rowacc = log_sigmoid(grp_sum16(dot8(c0, c1, x0, x1)));
#pragma unroll
        for (int k = 0; k < K_; ++k) {
            int nk = __shfl(myidx, (lane & 48) | k, 64);
            const float* nrow = negTable + (size_t)nk * (size_t)D_;
            float4 n0 = *(const float4*)(nrow + lw * 4);
            float4 n1 = *(const float4*)(nrow + 64 + lw * 4);
            rowacc += log_sigmoid(-grp_sum16(dot8(c0, c1, n0, n1)));
        }
        wsum += rowacc;
    }

    wsum += __shfl_xor(wsum, 16, 64);
    wsum += __shfl_xor(wsum, 32, 64);

    __shared__ float part[WAVES_PER_BLOCK];
    if (lane == 0) part[wave] = wsum;
    __syncthreads();
    if (threadIdx.x == 0) {
        float s = part[0] + part[1] + part[2] + part[3];
        atomicAdd(&acc[type], s);
    }
}

__global__ void finalize_kernel(const float* __restrict__ acc,
                                const float* __restrict__ hyp1,
                                const float* __restrict__ hyp2,
                                float* __restrict__ out)
{
    const float invB = 1.0f / (float)B_;
    float s1 = acc[0], s2 = acc[1], s3 = acc[2];
    out[0] = -(s1 * (invB / 9.0f) + hyp1[0] * s2 * (invB / 18.0f) + hyp2[0] * s3 * (invB / 18.0f));
}

extern "C" void kernel_launch(void* const* d_in, const int* in_sizes, int n_in,
                              void* d_out, int out_size, void* d_ws, size_t ws_size,
                              hipStream_t stream)
{
    const int*   countp    = (const int*)d_in[0];
    const int*   shuffle   = (const int*)d_in[1];
    const int*   nodes_idx = (const int*)d_in[2];
    const int*   neigh_idx = (const int*)d_in[3];
    const int*   neg1      = (const int*)d_in[4];
    const int*   neg2      = (const int*)d_in[5];
    const int*   neg3      = (const int*)d_in[6];
    const float* node_W    = (const float*)d_in[7];
    const float* neigh_W   = (const float*)d_in[8];
    const float* hyp1      = (const float*)d_in[9];
    const float* hyp2      = (const float*)d_in[10];

    float* acc = (float*)d_ws;
    (void)hipMemsetAsync(acc, 0, 3 * sizeof(float), stream);

    dim3 block(256);

    if (ws_size >= WS_NEED) {
        uint2* nodeT  = (uint2*)((char*)d_ws + ACC_BYTES);
        uint2* neighT = (uint2*)((char*)d_ws + ACC_BYTES + FP8_TBL_BYTES);
        const int n8 = (int)(TBL_ELEMS / 8);                 // 9.6M per table
        cvt_fp8<<<4096, block, 0, stream>>>((const float4*)node_W,  nodeT,  n8);
        cvt_fp8<<<4096, block, 0, stream>>>((const float4*)neigh_W, neighT, n8);
        sgns_fp8<<<dim3(15 * BLOCKS_PER_TERM), block, 0, stream>>>(
            countp, shuffle, nodes_idx, neigh_idx, neg1, neg2, neg3,
            (const uint2*)nodeT, (const uint2*)neighT, acc);
    } else {
        sgns_f32<<<dim3(15 * BLOCKS_PER_TERM), block, 0, stream>>>(
            countp, shuffle, nodes_idx, neigh_idx, neg1, neg2, neg3,
            node_W, neigh_W, acc);
    }

    finalize_kernel<<<1, 1, 0, stream>>>(acc, hyp1, hyp2, (float*)d_out);
}

// Round 8
// 286.248 us; speedup vs baseline: 2.1387x; 1.0471x over previous
//
#include <hip/hip_runtime.h>

#define V_   3
#define N_   200000
#define D_   128
#define B_   32768
#define K_   10
#define TOT_ 65536

constexpr int BLOCKS_PER_TERM = 512;
constexpr int ROWS_PER_BLOCK  = B_ / BLOCKS_PER_TERM;             // 64
constexpr int WAVES_PER_BLOCK = 4;                                // 256 threads
constexpr int ROWS_PER_WAVE   = ROWS_PER_BLOCK / WAVES_PER_BLOCK; // 16
constexpr int GROUPS_PER_WAVE = 4;                                // 16 lanes/row
constexpr int ITERS           = ROWS_PER_WAVE / GROUPS_PER_WAVE;  // 4

constexpr size_t TBL_ELEMS     = (size_t)V_ * N_ * D_;    // 76.8e6 per table
constexpr size_t FP8_TBL_BYTES = TBL_ELEMS;               // 76.8 MB per table
constexpr size_t ACC_BYTES     = 256;
constexpr size_t WS_NEED       = ACC_BYTES + 2 * FP8_TBL_BYTES;

// Term schedule grouped by negative-sample table slice.
__device__ const int TMAP[15][3] = {
    {0, 0, 0}, {2, 1, 0}, {2, 2, 0},
    {0, 1, 1}, {2, 0, 1}, {2, 2, 1},
    {0, 2, 2}, {2, 0, 2}, {2, 1, 2},
    {1, 1, 0}, {1, 2, 0},
    {1, 0, 1}, {1, 2, 1},
    {1, 0, 2}, {1, 1, 2},
};

typedef float v2f __attribute__((ext_vector_type(2)));

template <int CTRL>
__device__ __forceinline__ float dpp_add(float v) {
    int x = __builtin_amdgcn_update_dpp(0, __float_as_int(v), CTRL, 0xF, 0xF, true);
    return v + __int_as_float(x);
}

// 16-lane sum on the VALU pipe.
__device__ __forceinline__ float grp_sum16(float v) {
    v = dpp_add<0xB1>(v);
    v = dpp_add<0x4E>(v);
    v = dpp_add<0x124>(v);
    v = dpp_add<0x128>(v);
    return v;
}

__device__ __forceinline__ float log_sigmoid(float x) {
    float ax = fabsf(x);
    return fminf(x, 0.f) - __logf(1.f + __expf(-ax));
}

// ---------------- fp8 e4m3 helpers (HW cvt; selectors constant) ----------------
__device__ __forceinline__ unsigned cvt4_fp8(float a, float b, float c, float d) {
    int v = __builtin_amdgcn_cvt_pk_fp8_f32(a, b, 0, false);
    v = __builtin_amdgcn_cvt_pk_fp8_f32(c, d, v, true);
    return (unsigned)v;
}
template <bool HI>
__device__ __forceinline__ v2f upk2(unsigned v) {
    return __builtin_amdgcn_cvt_pk_f32_fp8((int)v, HI);
}

// Fused conversion of both tables + acc zeroing (replaces memset + 2 launches).
__global__ __launch_bounds__(256) void cvt_fp8_both(
    const float4* __restrict__ srcA, const float4* __restrict__ srcB,
    uint2* __restrict__ dstA, uint2* __restrict__ dstB,
    float* __restrict__ acc, int n8)
{
    if (blockIdx.x == 0 && threadIdx.x < 8) acc[threadIdx.x] = 0.f;
    const int stride = gridDim.x * blockDim.x;
    const int tot = 2 * n8;
    for (int g = blockIdx.x * blockDim.x + threadIdx.x; g < tot; g += stride) {
        const float4* s;
        uint2* d;
        int gi;
        if (g < n8) { s = srcA; d = dstA; gi = g; }
        else        { s = srcB; d = dstB; gi = g - n8; }
        float4 a = s[2 * gi];
        float4 b = s[2 * gi + 1];
        uint2 o;
        o.x = cvt4_fp8(a.x, a.y, a.z, a.w);
        o.y = cvt4_fp8(b.x, b.y, b.z, b.w);
        d[gi] = o;
    }
}

// dot of this lane's 8 fp8 elements against pre-decoded center (4 x v2f),
// using packed f32 math (v_pk_fma_f32).
__device__ __forceinline__ float dotv(v2f c0, v2f c1, v2f c2, v2f c3, uint2 n) {
    v2f a0 = c0 * upk2<false>(n.x);
    v2f a1 = c1 * upk2<true>(n.x);
    a0 += c2 * upk2<false>(n.y);
    a1 += c3 * upk2<true>(n.y);
    v2f a = a0 + a1;
    return a.x + a.y;
}

// ---------------- fp8 gather kernel ----------------
// Tables: 16 uint2 per row (128 fp8). Lane lw loads uint2 -> 8 elements.
__global__ __launch_bounds__(256) void sgns_fp8(
    const int*   __restrict__ countp,
    const int*   __restrict__ shuffle,
    const int*   __restrict__ nodes_idx,
    const int*   __restrict__ neigh_idx,
    const int*   __restrict__ neg1,
    const int*   __restrict__ neg2,
    const int*   __restrict__ neg3,
    const uint2* __restrict__ nodeT,
    const uint2* __restrict__ neighT,
    float*       __restrict__ acc)
{
    const int slot = blockIdx.x / BLOCKS_PER_TERM;
    const int blk  = blockIdx.x % BLOCKS_PER_TERM;
    const int wave = threadIdx.x >> 6;
    const int lane = threadIdx.x & 63;
    const int grp  = lane >> 4;
    const int lw   = lane & 15;
    const int count = countp[0];

    const int type = TMAP[slot][0];
    const int i    = TMAP[slot][1];
    const int j    = TMAP[slot][2];

    const int*   negBase;
    const uint2* negTable;
    if (type == 0)      { negTable = neighT + (size_t)i * N_ * 16; negBase = neg1 + (size_t)i * B_ * K_; }
    else if (type == 1) { negTable = nodeT  + (size_t)j * N_ * 16; negBase = neg2 + (size_t)(j * V_ + i) * B_ * K_; }
    else                { negTable = neighT + (size_t)j * N_ * 16; negBase = neg3 + (size_t)(j * V_ + i) * B_ * K_; }

    float wsum = 0.f;
    const int rowbase = blk * ROWS_PER_BLOCK + wave * ROWS_PER_WAVE;

    for (int r = 0; r < ITERS; ++r) {
        const int b  = rowbase + r * GROUPS_PER_WAVE + grp;
        const int sh = shuffle[i * TOT_ + count + b];
        const int ns = nodes_idx[i * TOT_ + sh];

        uint2 c8 = nodeT[((size_t)i * N_ + ns) * 16 + lw];

        const uint2* xrow;
        if (type == 0) {
            int gs = neigh_idx[i * TOT_ + sh];
            xrow = neighT + ((size_t)i * N_ + gs) * 16;
        } else if (type == 1) {
            xrow = nodeT + ((size_t)j * N_ + ns) * 16;
        } else {
            int gs = neigh_idx[i * TOT_ + sh];
            xrow = neighT + ((size_t)j * N_ + gs) * 16;
        }
        uint2 x8 = xrow[lw];

        int myidx = (lw < K_) ? negBase[(size_t)b * K_ + lw] : 0;

        // Broadcast neg indices, then issue ALL 10 neg loads before reducing (MLP).
        uint2 nv[K_];
#pragma unroll
        for (int k = 0; k < K_; ++k) {
            int nk = __shfl(myidx, (lane & 48) | k, 64);
            nv[k] = negTable[(size_t)nk * 16 + lw];
        }

        v2f c0 = upk2<false>(c8.x), c1 = upk2<true>(c8.x);
        v2f c2 = upk2<false>(c8.y), c3 = upk2<true>(c8.y);

        float rowacc = log_sigmoid(grp_sum16(dotv(c0, c1, c2, c3, x8)));
#pragma unroll
        for (int k = 0; k < K_; ++k) {
            rowacc += log_sigmoid(-grp_sum16(dotv(c0, c1, c2, c3, nv[k])));
        }
        wsum += rowacc;
    }

    wsum += __shfl_xor(wsum, 16, 64);
    wsum += __shfl_xor(wsum, 32, 64);

    __shared__ float part[WAVES_PER_BLOCK];
    if (lane == 0) part[wave] = wsum;
    __syncthreads();
    if (threadIdx.x == 0) {
        float s = part[0] + part[1] + part[2] + part[3];
        atomicAdd(&acc[type], s);
    }
}

// ---------------- f32 fallback (proven round-3 kernel) ----------------
__device__ __forceinline__ float dot8(float4 a0, float4 a1, float4 b0, float4 b1) {
    float s = a0.x * b0.x;
    s = fmaf(a0.y, b0.y, s);
    s = fmaf(a0.z, b0.z, s);
    s = fmaf(a0.w, b0.w, s);
    s = fmaf(a1.x, b1.x, s);
    s = fmaf(a1.y, b1.y, s);
    s = fmaf(a1.z, b1.z, s);
    s = fmaf(a1.w, b1.w, s);
    return s;
}

__global__ __launch_bounds__(256) void sgns_f32(
    const int*   __restrict__ countp,
    const int*   __restrict__ shuffle,
    const int*   __restrict__ nodes_idx,
    const int*   __restrict__ neigh_idx,
    const int*   __restrict__ neg1,
    const int*   __restrict__ neg2,
    const int*   __restrict__ neg3,
    const float* __restrict__ node_W,
    const float* __restrict__ neigh_W,
    float*       __restrict__ acc)
{
    const int slot = blockIdx.x / BLOCKS_PER_TERM;
    const int blk  = blockIdx.x % BLOCKS_PER_TERM;
    const int wave = threadIdx.x >> 6;
    const int lane = threadIdx.x & 63;
    const int grp  = lane >> 4;
    const int lw   = lane & 15;
    const int count = countp[0];

    const int type = TMAP[slot][0];
    const int i    = TMAP[slot][1];
    const int j    = TMAP[slot][2];

    const int*   negBase;
    const float* negTable;
    if (type == 0)      { negTable = neigh_W + (size_t)i * N_ * D_; negBase = neg1 + (size_t)i * B_ * K_; }
    else if (type == 1) { negTable = node_W  + (size_t)j * N_ * D_; negBase = neg2 + (size_t)(j * V_ + i) * B_ * K_; }
    else                { negTable = neigh_W + (size_t)j * N_ * D_; negBase = neg3 + (size_t)(j * V_ + i) * B_ * K_; }

    float wsum = 0.f;
    const int rowbase = blk * ROWS_PER_BLOCK + wave * ROWS_PER_WAVE;

    for (int r = 0; r < ITERS; ++r) {
        const int b  = rowbase + r * GROUPS_PER_WAVE + grp;
        const int sh = shuffle[i * TOT_ + count + b];
        const int ns = nodes_idx[i * TOT_ + sh];

        const float* crow = node_W + ((size_t)i * N_ + ns) * (size_t)D_;
        float4 c0 = *(const float4*)(crow + lw * 4);
        float4 c1 = *(const float4*)(crow + 64 + lw * 4);

        const float* xrow;
        if (type == 0) {
            int gs = neigh_idx[i * TOT_ + sh];
            xrow = neigh_W + ((size_t)i * N_ + gs) * (size_t)D_;
        } else if (type == 1) {
            xrow = node_W + ((size_t)j * N_ + ns) * (size_t)D_;
        } else {
            int gs = neigh_idx[i * TOT_ + sh];
            xrow = neigh_W + ((size_t)j * N_ + gs) * (size_t)D_;
        }
        float4 x0 = *(const float4*)(xrow + lw * 4);
        float4 x1 = *(const float4*)(xrow + 64 + lw * 4);

        int myidx = (lw < K_) ? negBase[(size_t)b * K_ + lw] : 0;

        float rowacc = log_sigmoid(grp_sum16(dot8(c0, c1, x0, x1)));
#pragma unroll
        for (int k = 0; k < K_; ++k) {
            int nk = __shfl(myidx, (lane & 48) | k, 64);
            const float* nrow = negTable + (size_t)nk * (size_t)D_;
            float4 n0 = *(const float4*)(nrow + lw * 4);
            float4 n1 = *(const float4*)(nrow + 64 + lw * 4);
            rowacc += log_sigmoid(-grp_sum16(dot8(c0, c1, n0, n1)));
        }
        wsum += rowacc;
    }

    wsum += __shfl_xor(wsum, 16, 64);
    wsum += __shfl_xor(wsum, 32, 64);

    __shared__ float part[WAVES_PER_BLOCK];
    if (lane == 0) part[wave] = wsum;
    __syncthreads();
    if (threadIdx.x == 0) {
        float s = part[0] + part[1] + part[2] + part[3];
        atomicAdd(&acc[type], s);
    }
}

__global__ void finalize_kernel(const float* __restrict__ acc,
                                const float* __restrict__ hyp1,
                                const float* __restrict__ hyp2,
                                float* __restrict__ out)
{
    const float invB = 1.0f / (float)B_;
    float s1 = acc[0], s2 = acc[1], s3 = acc[2];
    out[0] = -(s1 * (invB / 9.0f) + hyp1[0] * s2 * (invB / 18.0f) + hyp2[0] * s3 * (invB / 18.0f));
}

extern "C" void kernel_launch(void* const* d_in, const int* in_sizes, int n_in,
                              void* d_out, int out_size, void* d_ws, size_t ws_size,
                              hipStream_t stream)
{
    const int*   countp    = (const int*)d_in[0];
    const int*   shuffle   = (const int*)d_in[1];
    const int*   nodes_idx = (const int*)d_in[2];
    const int*   neigh_idx = (const int*)d_in[3];
    const int*   neg1      = (const int*)d_in[4];
    const int*   neg2      = (const int*)d_in[5];
    const int*   neg3      = (const int*)d_in[6];
    const float* node_W    = (const float*)d_in[7];
    const float* neigh_W   = (const float*)d_in[8];
    const float* hyp1      = (const float*)d_in[9];
    const float* hyp2      = (const float*)d_in[10];

    float* acc = (float*)d_ws;
    dim3 block(256);

    if (ws_size >= WS_NEED) {
        uint2* nodeT  = (uint2*)((char*)d_ws + ACC_BYTES);
        uint2* neighT = (uint2*)((char*)d_ws + ACC_BYTES + FP8_TBL_BYTES);
        const int n8 = (int)(TBL_ELEMS / 8);                 // 9.6M per table
        cvt_fp8_both<<<8192, block, 0, stream>>>((const float4*)node_W, (const float4*)neigh_W,
                                                 nodeT, neighT, acc, n8);
        sgns_fp8<<<dim3(15 * BLOCKS_PER_TERM), block, 0, stream>>>(
            countp, shuffle, nodes_idx, neigh_idx, neg1, neg2, neg3,
            (const uint2*)nodeT, (const uint2*)neighT, acc);
    } else {
        (void)hipMemsetAsync(acc, 0, 3 * sizeof(float), stream);
        sgns_f32<<<dim3(15 * BLOCKS_PER_TERM), block, 0, stream>>>(
            countp, shuffle, nodes_idx, neigh_idx, neg1, neg2, neg3,
            node_W, neigh_W, acc);
    }

    finalize_kernel<<<1, 1, 0, stream>>>(acc, hyp1, hyp2, (float*)d_out);
}

// Round 9
// 278.749 us; speedup vs baseline: 2.1962x; 1.0269x over previous
//
#include <hip/hip_runtime.h>

#define V_   3
#define N_   200000
#define D_   128
#define B_   32768
#define K_   10
#define TOT_ 65536

constexpr int BLOCKS_PER_TERM = 512;
constexpr int ROWS_PER_BLOCK  = B_ / BLOCKS_PER_TERM;             // 64
constexpr int WAVES_PER_BLOCK = 4;                                // 256 threads
constexpr int ROWS_PER_WAVE   = ROWS_PER_BLOCK / WAVES_PER_BLOCK; // 16
constexpr int GROUPS_PER_WAVE = 4;                                // 16 lanes/row
constexpr int ITERS           = ROWS_PER_WAVE / GROUPS_PER_WAVE;  // 4

constexpr size_t TBL_ELEMS     = (size_t)V_ * N_ * D_;    // 76.8e6 per table
constexpr size_t FP8_TBL_BYTES = TBL_ELEMS;               // 76.8 MB per table
constexpr size_t ACC_BYTES     = 256;
constexpr size_t WS_NEED       = ACC_BYTES + 2 * FP8_TBL_BYTES;

// cvt geometry: 2 tables x 9.6M uint2-groups = 19.2M; 15000 blk x 256 thr x 5 it
constexpr int CVT_ITERS  = 5;
constexpr int CVT_BLOCKS = 15000;

// Term schedule grouped by negative-sample table slice.
__device__ const int TMAP[15][3] = {
    {0, 0, 0}, {2, 1, 0}, {2, 2, 0},
    {0, 1, 1}, {2, 0, 1}, {2, 2, 1},
    {0, 2, 2}, {2, 0, 2}, {2, 1, 2},
    {1, 1, 0}, {1, 2, 0},
    {1, 0, 1}, {1, 2, 1},
    {1, 0, 2}, {1, 1, 2},
};

typedef float v2f __attribute__((ext_vector_type(2)));

template <int CTRL>
__device__ __forceinline__ float dpp_add(float v) {
    int x = __builtin_amdgcn_update_dpp(0, __float_as_int(v), CTRL, 0xF, 0xF, true);
    return v + __int_as_float(x);
}

// 16-lane sum on the VALU pipe.
__device__ __forceinline__ float grp_sum16(float v) {
    v = dpp_add<0xB1>(v);
    v = dpp_add<0x4E>(v);
    v = dpp_add<0x124>(v);
    v = dpp_add<0x128>(v);
    return v;
}

__device__ __forceinline__ float log_sigmoid(float x) {
    float ax = fabsf(x);
    return fminf(x, 0.f) - __logf(1.f + __expf(-ax));
}

// ---------------- fp8 e4m3 helpers (HW cvt; selectors constant) ----------------
__device__ __forceinline__ unsigned cvt4_fp8(float a, float b, float c, float d) {
    int v = __builtin_amdgcn_cvt_pk_fp8_f32(a, b, 0, false);
    v = __builtin_amdgcn_cvt_pk_fp8_f32(c, d, v, true);
    return (unsigned)v;
}
template <bool HI>
__device__ __forceinline__ v2f upk2(unsigned v) {
    return __builtin_amdgcn_cvt_pk_f32_fp8((int)v, HI);
}

// Fused conversion of both tables + acc zeroing. Exactly CVT_ITERS groups per
// thread, fully unrolled: all 2*CVT_ITERS float4 loads issue before any use.
__global__ __launch_bounds__(256) void cvt_fp8_both(
    const float4* __restrict__ srcA, const float4* __restrict__ srcB,
    uint2* __restrict__ dstA, uint2* __restrict__ dstB,
    float* __restrict__ acc, int n8)
{
    if (blockIdx.x == 0 && threadIdx.x < 8) acc[threadIdx.x] = 0.f;
    const int stride = CVT_BLOCKS * 256;
    const int tid = blockIdx.x * 256 + threadIdx.x;

    float4 a[CVT_ITERS], b[CVT_ITERS];
#pragma unroll
    for (int it = 0; it < CVT_ITERS; ++it) {
        const int g  = tid + it * stride;
        const float4* s = (g < n8) ? srcA : srcB;
        const int gi = (g < n8) ? g : g - n8;
        a[it] = s[2 * (size_t)gi];
        b[it] = s[2 * (size_t)gi + 1];
    }
#pragma unroll
    for (int it = 0; it < CVT_ITERS; ++it) {
        const int g  = tid + it * stride;
        uint2* d = (g < n8) ? dstA : dstB;
        const int gi = (g < n8) ? g : g - n8;
        uint2 o;
        o.x = cvt4_fp8(a[it].x, a[it].y, a[it].z, a[it].w);
        o.y = cvt4_fp8(b[it].x, b[it].y, b[it].z, b[it].w);
        d[gi] = o;
    }
}

// dot of this lane's 8 fp8 elements against pre-decoded center (4 x v2f),
// using packed f32 math (v_pk_fma_f32).
__device__ __forceinline__ float dotv(v2f c0, v2f c1, v2f c2, v2f c3, uint2 n) {
    v2f a0 = c0 * upk2<false>(n.x);
    v2f a1 = c1 * upk2<true>(n.x);
    a0 += c2 * upk2<false>(n.y);
    a1 += c3 * upk2<true>(n.y);
    v2f a = a0 + a1;
    return a.x + a.y;
}

// ---------------- fp8 gather kernel ----------------
__global__ __launch_bounds__(256) void sgns_fp8(
    const int*   __restrict__ countp,
    const int*   __restrict__ shuffle,
    const int*   __restrict__ nodes_idx,
    const int*   __restrict__ neigh_idx,
    const int*   __restrict__ neg1,
    const int*   __restrict__ neg2,
    const int*   __restrict__ neg3,
    const uint2* __restrict__ nodeT,
    const uint2* __restrict__ neighT,
    float*       __restrict__ acc)
{
    const int slot = blockIdx.x / BLOCKS_PER_TERM;
    const int blk  = blockIdx.x % BLOCKS_PER_TERM;
    const int wave = threadIdx.x >> 6;
    const int lane = threadIdx.x & 63;
    const int grp  = lane >> 4;
    const int lw   = lane & 15;
    const int count = countp[0];

    const int type = TMAP[slot][0];
    const int i    = TMAP[slot][1];
    const int j    = TMAP[slot][2];

    const int*   negBase;
    const uint2* negTable;
    if (type == 0)      { negTable = neighT + (size_t)i * N_ * 16; negBase = neg1 + (size_t)i * B_ * K_; }
    else if (type == 1) { negTable = nodeT  + (size_t)j * N_ * 16; negBase = neg2 + (size_t)(j * V_ + i) * B_ * K_; }
    else                { negTable = neighT + (size_t)j * N_ * 16; negBase = neg3 + (size_t)(j * V_ + i) * B_ * K_; }

    float wsum = 0.f;
    const int rowbase = blk * ROWS_PER_BLOCK + wave * ROWS_PER_WAVE;

    for (int r = 0; r < ITERS; ++r) {
        const int b  = rowbase + r * GROUPS_PER_WAVE + grp;
        const int sh = shuffle[i * TOT_ + count + b];
        const int ns = nodes_idx[i * TOT_ + sh];

        uint2 c8 = nodeT[((size_t)i * N_ + ns) * 16 + lw];

        const uint2* xrow;
        if (type == 0) {
            int gs = neigh_idx[i * TOT_ + sh];
            xrow = neighT + ((size_t)i * N_ + gs) * 16;
        } else if (type == 1) {
            xrow = nodeT + ((size_t)j * N_ + ns) * 16;
        } else {
            int gs = neigh_idx[i * TOT_ + sh];
            xrow = neighT + ((size_t)j * N_ + gs) * 16;
        }
        uint2 x8 = xrow[lw];

        int myidx = (lw < K_) ? negBase[(size_t)b * K_ + lw] : 0;

        // Broadcast neg indices, then issue ALL 10 neg loads before reducing (MLP).
        uint2 nv[K_];
#pragma unroll
        for (int k = 0; k < K_; ++k) {
            int nk = __shfl(myidx, (lane & 48) | k, 64);
            nv[k] = negTable[(size_t)nk * 16 + lw];
        }

        v2f c0 = upk2<false>(c8.x), c1 = upk2<true>(c8.x);
        v2f c2 = upk2<false>(c8.y), c3 = upk2<true>(c8.y);

        float rowacc = log_sigmoid(grp_sum16(dotv(c0, c1, c2, c3, x8)));
#pragma unroll
        for (int k = 0; k < K_; ++k) {
            rowacc += log_sigmoid(-grp_sum16(dotv(c0, c1, c2, c3, nv[k])));
        }
        wsum += rowacc;
    }

    wsum += __shfl_xor(wsum, 16, 64);
    wsum += __shfl_xor(wsum, 32, 64);

    __shared__ float part[WAVES_PER_BLOCK];
    if (lane == 0) part[wave] = wsum;
    __syncthreads();
    if (threadIdx.x == 0) {
        float s = part[0] + part[1] + part[2] + part[3];
        atomicAdd(&acc[type], s);
    }
}

// ---------------- f32 fallback (proven round-3 kernel) ----------------
__device__ __forceinline__ float dot8(float4 a0, float4 a1, float4 b0, float4 b1) {
    float s = a0.x * b0.x;
    s = fmaf(a0.y, b0.y, s);
    s = fmaf(a0.z, b0.z, s);
    s = fmaf(a0.w, b0.w, s);
    s = fmaf(a1.x, b1.x, s);
    s = fmaf(a1.y, b1.y, s);
    s = fmaf(a1.z, b1.z, s);
    s = fmaf(a1.w, b1.w, s);
    return s;
}

__global__ __launch_bounds__(256) void sgns_f32(
    const int*   __restrict__ countp,
    const int*   __restrict__ shuffle,
    const int*   __restrict__ nodes_idx,
    const int*   __restrict__ neigh_idx,
    const int*   __restrict__ neg1,
    const int*   __restrict__ neg2,
    const int*   __restrict__ neg3,
    const float* __restrict__ node_W,
    const float* __restrict__ neigh_W,
    float*       __restrict__ acc)
{
    const int slot = blockIdx.x / BLOCKS_PER_TERM;
    const int blk  = blockIdx.x % BLOCKS_PER_TERM;
    const int wave = threadIdx.x >> 6;
    const int lane = threadIdx.x & 63;
    const int grp  = lane >> 4;
    const int lw   = lane & 15;
    const int count = countp[0];

    const int type = TMAP[slot][0];
    const int i    = TMAP[slot][1];
    const int j    = TMAP[slot][2];

    const int*   negBase;
    const float* negTable;
    if (type == 0)      { negTable = neigh_W + (size_t)i * N_ * D_; negBase = neg1 + (size_t)i * B_ * K_; }
    else if (type == 1) { negTable = node_W  + (size_t)j * N_ * D_; negBase = neg2 + (size_t)(j * V_ + i) * B_ * K_; }
    else                { negTable = neigh_W + (size_t)j * N_ * D_; negBase = neg3 + (size_t)(j * V_ + i) * B_ * K_; }

    float wsum = 0.f;
    const int rowbase = blk * ROWS_PER_BLOCK + wave * ROWS_PER_WAVE;

    for (int r = 0; r < ITERS; ++r) {
        const int b  = rowbase + r * GROUPS_PER_WAVE + grp;
        const int sh = shuffle[i * TOT_ + count + b];
        const int ns = nodes_idx[i * TOT_ + sh];

        const float* crow = node_W + ((size_t)i * N_ + ns) * (size_t)D_;
        float4 c0 = *(const float4*)(crow + lw * 4);
        float4 c1 = *(const float4*)(crow + 64 + lw * 4);

        const float* xrow;
        if (type == 0) {
            int gs = neigh_idx[i * TOT_ + sh];
            xrow = neigh_W + ((size_t)i * N_ + gs) * (size_t)D_;
        } else if (type == 1) {
            xrow = node_W + ((size_t)j * N_ + ns) * (size_t)D_;
        } else {
            int gs = neigh_idx[i * TOT_ + sh];
            xrow = neigh_W + ((size_t)j * N_ + gs) * (size_t)D_;
        }
        float4 x0 = *(const float4*)(xrow + lw * 4);
        float4 x1 = *(const float4*)(xrow + 64 + lw * 4);

        int myidx = (lw < K_) ? negBase[(size_t)b * K_ + lw] : 0;

        float rowacc = log_sigmoid(grp_sum16(dot8(c0, c1, x0, x1)));
#pragma unroll
        for (int k = 0; k < K_; ++k) {
            int nk = __shfl(myidx, (lane & 48) | k, 64);
            const float* nrow = negTable + (size_t)nk * (size_t)D_;
            float4 n0 = *(const float4*)(nrow + lw * 4);
            float4 n1 = *(const float4*)(nrow + 64 + lw * 4);
            rowacc += log_sigmoid(-grp_sum16(dot8(c0, c1, n0, n1)));
        }
        wsum += rowacc;
    }

    wsum += __shfl_xor(wsum, 16, 64);
    wsum += __shfl_xor(wsum, 32, 64);

    __shared__ float part[WAVES_PER_BLOCK];
    if (lane == 0) part[wave] = wsum;
    __syncthreads();
    if (threadIdx.x == 0) {
        float s = part[0] + part[1] + part[2] + part[3];
        atomicAdd(&acc[type], s);
    }
}

__global__ void finalize_kernel(const float* __restrict__ acc,
                                const float* __restrict__ hyp1,
                                const float* __restrict__ hyp2,
                                float* __restrict__ out)
{
    const float invB = 1.0f / (float)B_;
    float s1 = acc[0], s2 = acc[1], s3 = acc[2];
    out[0] = -(s1 * (invB / 9.0f) + hyp1[0] * s2 * (invB / 18.0f) + hyp2[0] * s3 * (invB / 18.0f));
}

extern "C" void kernel_launch(void* const* d_in, const int* in_sizes, int n_in,
                              void* d_out, int out_size, void* d_ws, size_t ws_size,
                              hipStream_t stream)
{
    const int*   countp    = (const int*)d_in[0];
    const int*   shuffle   = (const int*)d_in[1];
    const int*   nodes_idx = (const int*)d_in[2];
    const int*   neigh_idx = (const int*)d_in[3];
    const int*   neg1      = (const int*)d_in[4];
    const int*   neg2      = (const int*)d_in[5];
    const int*   neg3      = (const int*)d_in[6];
    const float* node_W    = (const float*)d_in[7];
    const float* neigh_W   = (const float*)d_in[8];
    const float* hyp1      = (const float*)d_in[9];
    const float* hyp2      = (const float*)d_in[10];

    float* acc = (float*)d_ws;
    dim3 block(256);

    if (ws_size >= WS_NEED) {
        uint2* nodeT  = (uint2*)((char*)d_ws + ACC_BYTES);
        uint2* neighT = (uint2*)((char*)d_ws + ACC_BYTES + FP8_TBL_BYTES);
        const int n8 = (int)(TBL_ELEMS / 8);                 // 9.6M per table
        cvt_fp8_both<<<CVT_BLOCKS, block, 0, stream>>>((const float4*)node_W, (const float4*)neigh_W,
                                                       nodeT, neighT, acc, n8);
        sgns_fp8<<<dim3(15 * BLOCKS_PER_TERM), block, 0, stream>>>(
            countp, shuffle, nodes_idx, neigh_idx, neg1, neg2, neg3,
            (const uint2*)nodeT, (const uint2*)neighT, acc);
    } else {
        (void)hipMemsetAsync(acc, 0, 3 * sizeof(float), stream);
        sgns_f32<<<dim3(15 * BLOCKS_PER_TERM), block, 0, stream>>>(
            countp, shuffle, nodes_idx, neigh_idx, neg1, neg2, neg3,
            node_W, neigh_W, acc);
    }

    finalize_kernel<<<1, 1, 0, stream>>>(acc, hyp1, hyp2, (float*)d_out);
}

// Round 11
// 265.083 us; speedup vs baseline: 2.3095x; 1.0516x over previous
//
#include <hip/hip_runtime.h>

#define V_   3
#define N_   200000
#define D_   128
#define B_   32768
#define K_   10
#define TOT_ 65536

constexpr int BLOCKS_PER_TERM = 512;
constexpr int ROWS_PER_BLOCK  = B_ / BLOCKS_PER_TERM;             // 64
constexpr int WAVES_PER_BLOCK = 4;                                // 256 threads
constexpr int ROWS_PER_WAVE   = ROWS_PER_BLOCK / WAVES_PER_BLOCK; // 16
constexpr int GROUPS_PER_WAVE = 4;                                // 16 lanes/row
constexpr int ITERS           = ROWS_PER_WAVE / GROUPS_PER_WAVE;  // 4

constexpr size_t TBL_ELEMS     = (size_t)V_ * N_ * D_;    // 76.8e6 per table
constexpr size_t FP8_TBL_BYTES = TBL_ELEMS;               // 76.8 MB per table
constexpr size_t ACC_BYTES     = 256;
constexpr size_t WS_NEED       = ACC_BYTES + 2 * FP8_TBL_BYTES;

// cvt geometry: per table 19.2M float4 items; 15000 blk x 256 thr x 5 iters
// per table (10 total). Exact: 15000*256*5 = 19,200,000 = TBL_ELEMS/4.
constexpr int    CVT_BLOCKS  = 15000;
constexpr int    CVT_THREADS = CVT_BLOCKS * 256;          // 3,840,000

// Term schedule grouped by negative-sample table slice.
__device__ const int TMAP[15][3] = {
    {0, 0, 0}, {2, 1, 0}, {2, 2, 0},
    {0, 1, 1}, {2, 0, 1}, {2, 2, 1},
    {0, 2, 2}, {2, 0, 2}, {2, 1, 2},
    {1, 1, 0}, {1, 2, 0},
    {1, 0, 1}, {1, 2, 1},
    {1, 0, 2}, {1, 1, 2},
};

typedef float v2f __attribute__((ext_vector_type(2)));
typedef float v4f __attribute__((ext_vector_type(4)));

template <int CTRL>
__device__ __forceinline__ float dpp_add(float v) {
    int x = __builtin_amdgcn_update_dpp(0, __float_as_int(v), CTRL, 0xF, 0xF, true);
    return v + __int_as_float(x);
}

// 16-lane sum on the VALU pipe.
__device__ __forceinline__ float grp_sum16(float v) {
    v = dpp_add<0xB1>(v);
    v = dpp_add<0x4E>(v);
    v = dpp_add<0x124>(v);
    v = dpp_add<0x128>(v);
    return v;
}

__device__ __forceinline__ float log_sigmoid(float x) {
    float ax = fabsf(x);
    return fminf(x, 0.f) - __logf(1.f + __expf(-ax));
}

// ---------------- fp8 e4m3 helpers (HW cvt; selectors constant) ----------------
__device__ __forceinline__ unsigned cvt4_fp8(float a, float b, float c, float d) {
    int v = __builtin_amdgcn_cvt_pk_fp8_f32(a, b, 0, false);
    v = __builtin_amdgcn_cvt_pk_fp8_f32(c, d, v, true);
    return (unsigned)v;
}
template <bool HI>
__device__ __forceinline__ v2f upk2(unsigned v) {
    return __builtin_amdgcn_cvt_pk_f32_fp8((int)v, HI);
}

// Fused conversion of both tables + acc zeroing.
// Dense: one v4f per thread per iteration -> one uint (4 fp8).
// All 10 loads issued (non-temporal, read-once) before sched_barrier(0);
// converts/stores after. Compiler cannot re-serialize the batch.
__global__ __launch_bounds__(256) void cvt_fp8_both(
    const v4f* __restrict__ srcA, const v4f* __restrict__ srcB,
    unsigned* __restrict__ dstA, unsigned* __restrict__ dstB,
    float* __restrict__ acc)
{
    if (blockIdx.x == 0 && threadIdx.x < 8) acc[threadIdx.x] = 0.f;
    const size_t tid = (size_t)blockIdx.x * 256 + threadIdx.x;

    v4f va0, va1, va2, va3, va4, vb0, vb1, vb2, vb3, vb4;
    va0 = __builtin_nontemporal_load(&srcA[tid + 0ul * CVT_THREADS]);
    va1 = __builtin_nontemporal_load(&srcA[tid + 1ul * CVT_THREADS]);
    va2 = __builtin_nontemporal_load(&srcA[tid + 2ul * CVT_THREADS]);
    va3 = __builtin_nontemporal_load(&srcA[tid + 3ul * CVT_THREADS]);
    va4 = __builtin_nontemporal_load(&srcA[tid + 4ul * CVT_THREADS]);
    vb0 = __builtin_nontemporal_load(&srcB[tid + 0ul * CVT_THREADS]);
    vb1 = __builtin_nontemporal_load(&srcB[tid + 1ul * CVT_THREADS]);
    vb2 = __builtin_nontemporal_load(&srcB[tid + 2ul * CVT_THREADS]);
    vb3 = __builtin_nontemporal_load(&srcB[tid + 3ul * CVT_THREADS]);
    vb4 = __builtin_nontemporal_load(&srcB[tid + 4ul * CVT_THREADS]);
    __builtin_amdgcn_sched_barrier(0);

    dstA[tid + 0ul * CVT_THREADS] = cvt4_fp8(va0.x, va0.y, va0.z, va0.w);
    dstA[tid + 1ul * CVT_THREADS] = cvt4_fp8(va1.x, va1.y, va1.z, va1.w);
    dstA[tid + 2ul * CVT_THREADS] = cvt4_fp8(va2.x, va2.y, va2.z, va2.w);
    dstA[tid + 3ul * CVT_THREADS] = cvt4_fp8(va3.x, va3.y, va3.z, va3.w);
    dstA[tid + 4ul * CVT_THREADS] = cvt4_fp8(va4.x, va4.y, va4.z, va4.w);
    dstB[tid + 0ul * CVT_THREADS] = cvt4_fp8(vb0.x, vb0.y, vb0.z, vb0.w);
    dstB[tid + 1ul * CVT_THREADS] = cvt4_fp8(vb1.x, vb1.y, vb1.z, vb1.w);
    dstB[tid + 2ul * CVT_THREADS] = cvt4_fp8(vb2.x, vb2.y, vb2.z, vb2.w);
    dstB[tid + 3ul * CVT_THREADS] = cvt4_fp8(vb3.x, vb3.y, vb3.z, vb3.w);
    dstB[tid + 4ul * CVT_THREADS] = cvt4_fp8(vb4.x, vb4.y, vb4.z, vb4.w);
}

// dot of this lane's 8 fp8 elements against pre-decoded center (4 x v2f),
// using packed f32 math (v_pk_fma_f32).
__device__ __forceinline__ float dotv(v2f c0, v2f c1, v2f c2, v2f c3, uint2 n) {
    v2f a0 = c0 * upk2<false>(n.x);
    v2f a1 = c1 * upk2<true>(n.x);
    a0 += c2 * upk2<false>(n.y);
    a1 += c3 * upk2<true>(n.y);
    v2f a = a0 + a1;
    return a.x + a.y;
}

// ---------------- fp8 gather kernel ----------------
__global__ __launch_bounds__(256) void sgns_fp8(
    const int*   __restrict__ countp,
    const int*   __restrict__ shuffle,
    const int*   __restrict__ nodes_idx,
    const int*   __restrict__ neigh_idx,
    const int*   __restrict__ neg1,
    const int*   __restrict__ neg2,
    const int*   __restrict__ neg3,
    const uint2* __restrict__ nodeT,
    const uint2* __restrict__ neighT,
    float*       __restrict__ acc)
{
    const int slot = blockIdx.x / BLOCKS_PER_TERM;
    const int blk  = blockIdx.x % BLOCKS_PER_TERM;
    const int wave = threadIdx.x >> 6;
    const int lane = threadIdx.x & 63;
    const int grp  = lane >> 4;
    const int lw   = lane & 15;
    const int count = countp[0];

    const int type = TMAP[slot][0];
    const int i    = TMAP[slot][1];
    const int j    = TMAP[slot][2];

    const int*   negBase;
    const uint2* negTable;
    if (type == 0)      { negTable = neighT + (size_t)i * N_ * 16; negBase = neg1 + (size_t)i * B_ * K_; }
    else if (type == 1) { negTable = nodeT  + (size_t)j * N_ * 16; negBase = neg2 + (size_t)(j * V_ + i) * B_ * K_; }
    else                { negTable = neighT + (size_t)j * N_ * 16; negBase = neg3 + (size_t)(j * V_ + i) * B_ * K_; }

    float wsum = 0.f;
    const int rowbase = blk * ROWS_PER_BLOCK + wave * ROWS_PER_WAVE;

    for (int r = 0; r < ITERS; ++r) {
        const int b  = rowbase + r * GROUPS_PER_WAVE + grp;
        const int sh = shuffle[i * TOT_ + count + b];
        const int ns = nodes_idx[i * TOT_ + sh];

        uint2 c8 = nodeT[((size_t)i * N_ + ns) * 16 + lw];

        const uint2* xrow;
        if (type == 0) {
            int gs = neigh_idx[i * TOT_ + sh];
            xrow = neighT + ((size_t)i * N_ + gs) * 16;
        } else if (type == 1) {
            xrow = nodeT + ((size_t)j * N_ + ns) * 16;
        } else {
            int gs = neigh_idx[i * TOT_ + sh];
            xrow = neighT + ((size_t)j * N_ + gs) * 16;
        }
        uint2 x8 = xrow[lw];

        int myidx = (lw < K_) ? negBase[(size_t)b * K_ + lw] : 0;

        // Broadcast neg indices, then issue ALL 10 neg loads before reducing (MLP).
        uint2 nv[K_];
#pragma unroll
        for (int k = 0; k < K_; ++k) {
            int nk = __shfl(myidx, (lane & 48) | k, 64);
            nv[k] = negTable[(size_t)nk * 16 + lw];
        }

        v2f c0 = upk2<false>(c8.x), c1 = upk2<true>(c8.x);
        v2f c2 = upk2<false>(c8.y), c3 = upk2<true>(c8.y);

        float rowacc = log_sigmoid(grp_sum16(dotv(c0, c1, c2, c3, x8)));
#pragma unroll
        for (int k = 0; k < K_; ++k) {
            rowacc += log_sigmoid(-grp_sum16(dotv(c0, c1, c2, c3, nv[k])));
        }
        wsum += rowacc;
    }

    wsum += __shfl_xor(wsum, 16, 64);
    wsum += __shfl_xor(wsum, 32, 64);

    __shared__ float part[WAVES_PER_BLOCK];
    if (lane == 0) part[wave] = wsum;
    __syncthreads();
    if (threadIdx.x == 0) {
        float s = part[0] + part[1] + part[2] + part[3];
        atomicAdd(&acc[type], s);
    }
}

// ---------------- f32 fallback (proven round-3 kernel) ----------------
__device__ __forceinline__ float dot8(float4 a0, float4 a1, float4 b0, float4 b1) {
    float s = a0.x * b0.x;
    s = fmaf(a0.y, b0.y, s);
    s = fmaf(a0.z, b0.z, s);
    s = fmaf(a0.w, b0.w, s);
    s = fmaf(a1.x, b1.x, s);
    s = fmaf(a1.y, b1.y, s);
    s = fmaf(a1.z, b1.z, s);
    s = fmaf(a1.w, b1.w, s);
    return s;
}

__global__ __launch_bounds__(256) void sgns_f32(
    const int*   __restrict__ countp,
    const int*   __restrict__ shuffle,
    const int*   __restrict__ nodes_idx,
    const int*   __restrict__ neigh_idx,
    const int*   __restrict__ neg1,
    const int*   __restrict__ neg2,
    const int*   __restrict__ neg3,
    const float* __restrict__ node_W,
    const float* __restrict__ neigh_W,
    float*       __restrict__ acc)
{
    const int slot = blockIdx.x / BLOCKS_PER_TERM;
    const int blk  = blockIdx.x % BLOCKS_PER_TERM;
    const int wave = threadIdx.x >> 6;
    const int lane = threadIdx.x & 63;
    const int grp  = lane >> 4;
    const int lw   = lane & 15;
    const int count = countp[0];

    const int type = TMAP[slot][0];
    const int i    = TMAP[slot][1];
    const int j    = TMAP[slot][2];

    const int*   negBase;
    const float* negTable;
    if (type == 0)      { negTable = neigh_W + (size_t)i * N_ * D_; negBase = neg1 + (size_t)i * B_ * K_; }
    else if (type == 1) { negTable = node_W  + (size_t)j * N_ * D_; negBase = neg2 + (size_t)(j * V_ + i) * B_ * K_; }
    else                { negTable = neigh_W + (size_t)j * N_ * D_; negBase = neg3 + (size_t)(j * V_ + i) * B_ * K_; }

    float wsum = 0.f;
    const int rowbase = blk * ROWS_PER_BLOCK + wave * ROWS_PER_WAVE;

    for (int r = 0; r < ITERS; ++r) {
        const int b  = rowbase + r * GROUPS_PER_WAVE + grp;
        const int sh = shuffle[i * TOT_ + count + b];
        const int ns = nodes_idx[i * TOT_ + sh];

        const float* crow = node_W + ((size_t)i * N_ + ns) * (size_t)D_;
        float4 c0 = *(const float4*)(crow + lw * 4);
        float4 c1 = *(const float4*)(crow + 64 + lw * 4);

        const float* xrow;
        if (type == 0) {
            int gs = neigh_idx[i * TOT_ + sh];
            xrow = neigh_W + ((size_t)i * N_ + gs) * (size_t)D_;
        } else if (type == 1) {
            xrow = node_W + ((size_t)j * N_ + ns) * (size_t)D_;
        } else {
            int gs = neigh_idx[i * TOT_ + sh];
            xrow = neigh_W + ((size_t)j * N_ + gs) * (size_t)D_;
        }
        float4 x0 = *(const float4*)(xrow + lw * 4);
        float4 x1 = *(const float4*)(xrow + 64 + lw * 4);

        int myidx = (lw < K_) ? negBase[(size_t)b * K_ + lw] : 0;

        float rowacc = log_sigmoid(grp_sum16(dot8(c0, c1, x0, x1)));
#pragma unroll
        for (int k = 0; k < K_; ++k) {
            int nk = __shfl(myidx, (lane & 48) | k, 64);
            const float* nrow = negTable + (size_t)nk * (size_t)D_;
            float4 n0 = *(const float4*)(nrow + lw * 4);
            float4 n1 = *(const float4*)(nrow + 64 + lw * 4);
            rowacc += log_sigmoid(-grp_sum16(dot8(c0, c1, n0, n1)));
        }
        wsum += rowacc;
    }

    wsum += __shfl_xor(wsum, 16, 64);
    wsum += __shfl_xor(wsum, 32, 64);

    __shared__ float part[WAVES_PER_BLOCK];
    if (lane == 0) part[wave] = wsum;
    __syncthreads();
    if (threadIdx.x == 0) {
        float s = part[0] + part[1] + part[2] + part[3];
        atomicAdd(&acc[type], s);
    }
}

__global__ void finalize_kernel(const float* __restrict__ acc,
                                const float* __restrict__ hyp1,
                                const float* __restrict__ hyp2,
                                float* __restrict__ out)
{
    const float invB = 1.0f / (float)B_;
    float s1 = acc[0], s2 = acc[1], s3 = acc[2];
    out[0] = -(s1 * (invB / 9.0f) + hyp1[0] * s2 * (invB / 18.0f) + hyp2[0] * s3 * (invB / 18.0f));
}

extern "C" void kernel_launch(void* const* d_in, const int* in_sizes, int n_in,
                              void* d_out, int out_size, void* d_ws, size_t ws_size,
                              hipStream_t stream)
{
    const int*   countp    = (const int*)d_in[0];
    const int*   shuffle   = (const int*)d_in[1];
    const int*   nodes_idx = (const int*)d_in[2];
    const int*   neigh_idx = (const int*)d_in[3];
    const int*   neg1      = (const int*)d_in[4];
    const int*   neg2      = (const int*)d_in[5];
    const int*   neg3      = (const int*)d_in[6];
    const float* node_W    = (const float*)d_in[7];
    const float* neigh_W   = (const float*)d_in[8];
    const float* hyp1      = (const float*)d_in[9];
    const float* hyp2      = (const float*)d_in[10];

    float* acc = (float*)d_ws;
    dim3 block(256);

    if (ws_size >= WS_NEED) {
        unsigned* nodeT  = (unsigned*)((char*)d_ws + ACC_BYTES);
        unsigned* neighT = (unsigned*)((char*)d_ws + ACC_BYTES + FP8_TBL_BYTES);
        cvt_fp8_both<<<CVT_BLOCKS, block, 0, stream>>>(
            (const v4f*)node_W, (const v4f*)neigh_W, nodeT, neighT, acc);
        sgns_fp8<<<dim3(15 * BLOCKS_PER_TERM), block, 0, stream>>>(
            countp, shuffle, nodes_idx, neigh_idx, neg1, neg2, neg3,
            (const uint2*)nodeT, (const uint2*)neighT, acc);
    } else {
        (void)hipMemsetAsync(acc, 0, 3 * sizeof(float), stream);
        sgns_f32<<<dim3(15 * BLOCKS_PER_TERM), block, 0, stream>>>(
            countp, shuffle, nodes_idx, neigh_idx, neg1, neg2, neg3,
            node_W, neigh_W, acc);
    }

    finalize_kernel<<<1, 1, 0, stream>>>(acc, hyp1, hyp2, (float*)d_out);
}

// Round 12
// 259.932 us; speedup vs baseline: 2.3552x; 1.0198x over previous
//
#include <hip/hip_runtime.h>

#define V_   3
#define N_   200000
#define D_   128
#define B_   32768
#define K_   10
#define TOT_ 65536

constexpr int BLOCKS_PER_TERM = 512;
constexpr int ROWS_PER_BLOCK  = B_ / BLOCKS_PER_TERM;             // 64
constexpr int WAVES_PER_BLOCK = 4;                                // 256 threads
constexpr int ROWS_PER_WAVE   = ROWS_PER_BLOCK / WAVES_PER_BLOCK; // 16
constexpr int GROUPS_PER_WAVE = 4;                                // 16 lanes/row
constexpr int ITERS           = ROWS_PER_WAVE / GROUPS_PER_WAVE;  // 4

constexpr size_t TBL_ELEMS     = (size_t)V_ * N_ * D_;    // 76.8e6 per table
constexpr size_t FP8_TBL_BYTES = TBL_ELEMS;               // 76.8 MB per table
constexpr size_t ACC_BYTES     = 256;
constexpr size_t WS_NEED       = ACC_BYTES + 2 * FP8_TBL_BYTES;

// cvt geometry: per table 19.2M float4 items; block-tile-contiguous:
// each block owns 1280 consecutive items per table (256 thr x 5 iters).
// 15000 * 1280 = 19,200,000 exact.
constexpr int CVT_BLOCKS = 15000;
constexpr int CVT_TILE   = 256 * 5;   // items per block per table

// Term schedule grouped by negative-sample table slice.
__device__ const int TMAP[15][3] = {
    {0, 0, 0}, {2, 1, 0}, {2, 2, 0},
    {0, 1, 1}, {2, 0, 1}, {2, 2, 1},
    {0, 2, 2}, {2, 0, 2}, {2, 1, 2},
    {1, 1, 0}, {1, 2, 0},
    {1, 0, 1}, {1, 2, 1},
    {1, 0, 2}, {1, 1, 2},
};

typedef float v2f __attribute__((ext_vector_type(2)));
typedef float v4f __attribute__((ext_vector_type(4)));

template <int CTRL>
__device__ __forceinline__ float dpp_add(float v) {
    int x = __builtin_amdgcn_update_dpp(0, __float_as_int(v), CTRL, 0xF, 0xF, true);
    return v + __int_as_float(x);
}

// 16-lane sum on the VALU pipe.
__device__ __forceinline__ float grp_sum16(float v) {
    v = dpp_add<0xB1>(v);
    v = dpp_add<0x4E>(v);
    v = dpp_add<0x124>(v);
    v = dpp_add<0x128>(v);
    return v;
}

__device__ __forceinline__ float log_sigmoid(float x) {
    float ax = fabsf(x);
    return fminf(x, 0.f) - __logf(1.f + __expf(-ax));
}

// ---------------- fp8 e4m3 helpers (HW cvt; selectors constant) ----------------
__device__ __forceinline__ unsigned cvt4_fp8(float a, float b, float c, float d) {
    int v = __builtin_amdgcn_cvt_pk_fp8_f32(a, b, 0, false);
    v = __builtin_amdgcn_cvt_pk_fp8_f32(c, d, v, true);
    return (unsigned)v;
}
template <bool HI>
__device__ __forceinline__ v2f upk2(unsigned v) {
    return __builtin_amdgcn_cvt_pk_f32_fp8((int)v, HI);
}

// Fused conversion of both tables + acc zeroing.
// Block-tile-contiguous: block b owns items [b*1280, (b+1)*1280) of each
// table; thread t iter k handles item b*1280 + k*256 + t. Every load is a
// dense coalesced 4KB burst; each CU runs 2 compact read streams + 2 write
// streams (DRAM page locality). All 10 loads issue before sched_barrier(0).
__global__ __launch_bounds__(256) void cvt_fp8_both(
    const v4f* __restrict__ srcA, const v4f* __restrict__ srcB,
    unsigned* __restrict__ dstA, unsigned* __restrict__ dstB,
    float* __restrict__ acc)
{
    if (blockIdx.x == 0 && threadIdx.x < 8) acc[threadIdx.x] = 0.f;
    const size_t base = (size_t)blockIdx.x * CVT_TILE + threadIdx.x;

    v4f va0, va1, va2, va3, va4, vb0, vb1, vb2, vb3, vb4;
    va0 = __builtin_nontemporal_load(&srcA[base + 0 * 256]);
    va1 = __builtin_nontemporal_load(&srcA[base + 1 * 256]);
    va2 = __builtin_nontemporal_load(&srcA[base + 2 * 256]);
    va3 = __builtin_nontemporal_load(&srcA[base + 3 * 256]);
    va4 = __builtin_nontemporal_load(&srcA[base + 4 * 256]);
    vb0 = __builtin_nontemporal_load(&srcB[base + 0 * 256]);
    vb1 = __builtin_nontemporal_load(&srcB[base + 1 * 256]);
    vb2 = __builtin_nontemporal_load(&srcB[base + 2 * 256]);
    vb3 = __builtin_nontemporal_load(&srcB[base + 3 * 256]);
    vb4 = __builtin_nontemporal_load(&srcB[base + 4 * 256]);
    __builtin_amdgcn_sched_barrier(0);

    dstA[base + 0 * 256] = cvt4_fp8(va0.x, va0.y, va0.z, va0.w);
    dstA[base + 1 * 256] = cvt4_fp8(va1.x, va1.y, va1.z, va1.w);
    dstA[base + 2 * 256] = cvt4_fp8(va2.x, va2.y, va2.z, va2.w);
    dstA[base + 3 * 256] = cvt4_fp8(va3.x, va3.y, va3.z, va3.w);
    dstA[base + 4 * 256] = cvt4_fp8(va4.x, va4.y, va4.z, va4.w);
    dstB[base + 0 * 256] = cvt4_fp8(vb0.x, vb0.y, vb0.z, vb0.w);
    dstB[base + 1 * 256] = cvt4_fp8(vb1.x, vb1.y, vb1.z, vb1.w);
    dstB[base + 2 * 256] = cvt4_fp8(vb2.x, vb2.y, vb2.z, vb2.w);
    dstB[base + 3 * 256] = cvt4_fp8(vb3.x, vb3.y, vb3.z, vb3.w);
    dstB[base + 4 * 256] = cvt4_fp8(vb4.x, vb4.y, vb4.z, vb4.w);
}

// dot of this lane's 8 fp8 elements against pre-decoded center (4 x v2f),
// using packed f32 math (v_pk_fma_f32).
__device__ __forceinline__ float dotv(v2f c0, v2f c1, v2f c2, v2f c3, uint2 n) {
    v2f a0 = c0 * upk2<false>(n.x);
    v2f a1 = c1 * upk2<true>(n.x);
    a0 += c2 * upk2<false>(n.y);
    a1 += c3 * upk2<true>(n.y);
    v2f a = a0 + a1;
    return a.x + a.y;
}

// ---------------- fp8 gather kernel ----------------
__global__ __launch_bounds__(256) void sgns_fp8(
    const int*   __restrict__ countp,
    const int*   __restrict__ shuffle,
    const int*   __restrict__ nodes_idx,
    const int*   __restrict__ neigh_idx,
    const int*   __restrict__ neg1,
    const int*   __restrict__ neg2,
    const int*   __restrict__ neg3,
    const uint2* __restrict__ nodeT,
    const uint2* __restrict__ neighT,
    float*       __restrict__ acc)
{
    const int slot = blockIdx.x / BLOCKS_PER_TERM;
    const int blk  = blockIdx.x % BLOCKS_PER_TERM;
    const int wave = threadIdx.x >> 6;
    const int lane = threadIdx.x & 63;
    const int grp  = lane >> 4;
    const int lw   = lane & 15;
    const int count = countp[0];

    const int type = TMAP[slot][0];
    const int i    = TMAP[slot][1];
    const int j    = TMAP[slot][2];

    const int*   negBase;
    const uint2* negTable;
    if (type == 0)      { negTable = neighT + (size_t)i * N_ * 16; negBase = neg1 + (size_t)i * B_ * K_; }
    else if (type == 1) { negTable = nodeT  + (size_t)j * N_ * 16; negBase = neg2 + (size_t)(j * V_ + i) * B_ * K_; }
    else                { negTable = neighT + (size_t)j * N_ * 16; negBase = neg3 + (size_t)(j * V_ + i) * B_ * K_; }

    float wsum = 0.f;
    const int rowbase = blk * ROWS_PER_BLOCK + wave * ROWS_PER_WAVE;

    for (int r = 0; r < ITERS; ++r) {
        const int b  = rowbase + r * GROUPS_PER_WAVE + grp;
        const int sh = shuffle[i * TOT_ + count + b];
        const int ns = nodes_idx[i * TOT_ + sh];

        uint2 c8 = nodeT[((size_t)i * N_ + ns) * 16 + lw];

        const uint2* xrow;
        if (type == 0) {
            int gs = neigh_idx[i * TOT_ + sh];
            xrow = neighT + ((size_t)i * N_ + gs) * 16;
        } else if (type == 1) {
            xrow = nodeT + ((size_t)j * N_ + ns) * 16;
        } else {
            int gs = neigh_idx[i * TOT_ + sh];
            xrow = neighT + ((size_t)j * N_ + gs) * 16;
        }
        uint2 x8 = xrow[lw];

        int myidx = (lw < K_) ? negBase[(size_t)b * K_ + lw] : 0;

        // Broadcast neg indices, then issue ALL 10 neg loads before reducing (MLP).
        uint2 nv[K_];
#pragma unroll
        for (int k = 0; k < K_; ++k) {
            int nk = __shfl(myidx, (lane & 48) | k, 64);
            nv[k] = negTable[(size_t)nk * 16 + lw];
        }

        v2f c0 = upk2<false>(c8.x), c1 = upk2<true>(c8.x);
        v2f c2 = upk2<false>(c8.y), c3 = upk2<true>(c8.y);

        float rowacc = log_sigmoid(grp_sum16(dotv(c0, c1, c2, c3, x8)));
#pragma unroll
        for (int k = 0; k < K_; ++k) {
            rowacc += log_sigmoid(-grp_sum16(dotv(c0, c1, c2, c3, nv[k])));
        }
        wsum += rowacc;
    }

    wsum += __shfl_xor(wsum, 16, 64);
    wsum += __shfl_xor(wsum, 32, 64);

    __shared__ float part[WAVES_PER_BLOCK];
    if (lane == 0) part[wave] = wsum;
    __syncthreads();
    if (threadIdx.x == 0) {
        float s = part[0] + part[1] + part[2] + part[3];
        atomicAdd(&acc[type], s);
    }
}

// ---------------- f32 fallback (proven round-3 kernel) ----------------
__device__ __forceinline__ float dot8(float4 a0, float4 a1, float4 b0, float4 b1) {
    float s = a0.x * b0.x;
    s = fmaf(a0.y, b0.y, s);
    s = fmaf(a0.z, b0.z, s);
    s = fmaf(a0.w, b0.w, s);
    s = fmaf(a1.x, b1.x, s);
    s = fmaf(a1.y, b1.y, s);
    s = fmaf(a1.z, b1.z, s);
    s = fmaf(a1.w, b1.w, s);
    return s;
}

__global__ __launch_bounds__(256) void sgns_f32(
    const int*   __restrict__ countp,
    const int*   __restrict__ shuffle,
    const int*   __restrict__ nodes_idx,
    const int*   __restrict__ neigh_idx,
    const int*   __restrict__ neg1,
    const int*   __restrict__ neg2,
    const int*   __restrict__ neg3,
    const float* __restrict__ node_W,
    const float* __restrict__ neigh_W,
    float*       __restrict__ acc)
{
    const int slot = blockIdx.x / BLOCKS_PER_TERM;
    const int blk  = blockIdx.x % BLOCKS_PER_TERM;
    const int wave = threadIdx.x >> 6;
    const int lane = threadIdx.x & 63;
    const int grp  = lane >> 4;
    const int lw   = lane & 15;
    const int count = countp[0];

    const int type = TMAP[slot][0];
    const int i    = TMAP[slot][1];
    const int j    = TMAP[slot][2];

    const int*   negBase;
    const float* negTable;
    if (type == 0)      { negTable = neigh_W + (size_t)i * N_ * D_; negBase = neg1 + (size_t)i * B_ * K_; }
    else if (type == 1) { negTable = node_W  + (size_t)j * N_ * D_; negBase = neg2 + (size_t)(j * V_ + i) * B_ * K_; }
    else                { negTable = neigh_W + (size_t)j * N_ * D_; negBase = neg3 + (size_t)(j * V_ + i) * B_ * K_; }

    float wsum = 0.f;
    const int rowbase = blk * ROWS_PER_BLOCK + wave * ROWS_PER_WAVE;

    for (int r = 0; r < ITERS; ++r) {
        const int b  = rowbase + r * GROUPS_PER_WAVE + grp;
        const int sh = shuffle[i * TOT_ + count + b];
        const int ns = nodes_idx[i * TOT_ + sh];

        const float* crow = node_W + ((size_t)i * N_ + ns) * (size_t)D_;
        float4 c0 = *(const float4*)(crow + lw * 4);
        float4 c1 = *(const float4*)(crow + 64 + lw * 4);

        const float* xrow;
        if (type == 0) {
            int gs = neigh_idx[i * TOT_ + sh];
            xrow = neigh_W + ((size_t)i * N_ + gs) * (size_t)D_;
        } else if (type == 1) {
            xrow = node_W + ((size_t)j * N_ + ns) * (size_t)D_;
        } else {
            int gs = neigh_idx[i * TOT_ + sh];
            xrow = neigh_W + ((size_t)j * N_ + gs) * (size_t)D_;
        }
        float4 x0 = *(const float4*)(xrow + lw * 4);
        float4 x1 = *(const float4*)(xrow + 64 + lw * 4);

        int myidx = (lw < K_) ? negBase[(size_t)b * K_ + lw] : 0;

        float rowacc = log_sigmoid(grp_sum16(dot8(c0, c1, x0, x1)));
#pragma unroll
        for (int k = 0; k < K_; ++k) {
            int nk = __shfl(myidx, (lane & 48) | k, 64);
            const float* nrow = negTable + (size_t)nk * (size_t)D_;
            float4 n0 = *(const float4*)(nrow + lw * 4);
            float4 n1 = *(const float4*)(nrow + 64 + lw * 4);
            rowacc += log_sigmoid(-grp_sum16(dot8(c0, c1, n0, n1)));
        }
        wsum += rowacc;
    }

    wsum += __shfl_xor(wsum, 16, 64);
    wsum += __shfl_xor(wsum, 32, 64);

    __shared__ float part[WAVES_PER_BLOCK];
    if (lane == 0) part[wave] = wsum;
    __syncthreads();
    if (threadIdx.x == 0) {
        float s = part[0] + part[1] + part[2] + part[3];
        atomicAdd(&acc[type], s);
    }
}

__global__ void finalize_kernel(const float* __restrict__ acc,
                                const float* __restrict__ hyp1,
                                const float* __restrict__ hyp2,
                                float* __restrict__ out)
{
    const float invB = 1.0f / (float)B_;
    float s1 = acc[0], s2 = acc[1], s3 = acc[2];
    out[0] = -(s1 * (invB / 9.0f) + hyp1[0] * s2 * (invB / 18.0f) + hyp2[0] * s3 * (invB / 18.0f));
}

extern "C" void kernel_launch(void* const* d_in, const int* in_sizes, int n_in,
                              void* d_out, int out_size, void* d_ws, size_t ws_size,
                              hipStream_t stream)
{
    const int*   countp    = (const int*)d_in[0];
    const int*   shuffle   = (const int*)d_in[1];
    const int*   nodes_idx = (const int*)d_in[2];
    const int*   neigh_idx = (const int*)d_in[3];
    const int*   neg1      = (const int*)d_in[4];
    const int*   neg2      = (const int*)d_in[5];
    const int*   neg3      = (const int*)d_in[6];
    const float* node_W    = (const float*)d_in[7];
    const float* neigh_W   = (const float*)d_in[8];
    const float* hyp1      = (const float*)d_in[9];
    const float* hyp2      = (const float*)d_in[10];

    float* acc = (float*)d_ws;
    dim3 block(256);

    if (ws_size >= WS_NEED) {
        unsigned* nodeT  = (unsigned*)((char*)d_ws + ACC_BYTES);
        unsigned* neighT = (unsigned*)((char*)d_ws + ACC_BYTES + FP8_TBL_BYTES);
        cvt_fp8_both<<<CVT_BLOCKS, block, 0, stream>>>(
            (const v4f*)node_W, (const v4f*)neigh_W, nodeT, neighT, acc);
        sgns_fp8<<<dim3(15 * BLOCKS_PER_TERM), block, 0, stream>>>(
            countp, shuffle, nodes_idx, neigh_idx, neg1, neg2, neg3,
            (const uint2*)nodeT, (const uint2*)neighT, acc);
    } else {
        (void)hipMemsetAsync(acc, 0, 3 * sizeof(float), stream);
        sgns_f32<<<dim3(15 * BLOCKS_PER_TERM), block, 0, stream>>>(
            countp, shuffle, nodes_idx, neigh_idx, neg1, neg2, neg3,
            node_W, neigh_W, acc);
    }

    finalize_kernel<<<1, 1, 0, stream>>>(acc, hyp1, hyp2, (float*)d_out);
}

// Round 13
// 259.727 us; speedup vs baseline: 2.3571x; 1.0008x over previous
//
#include <hip/hip_runtime.h>

#define V_   3
#define N_   200000
#define D_   128
#define B_   32768
#define K_   10
#define TOT_ 65536

constexpr int BLOCKS_PER_TERM = 512;
constexpr int ROWS_PER_BLOCK  = B_ / BLOCKS_PER_TERM;             // 64
constexpr int WAVES_PER_BLOCK = 4;                                // 256 threads
constexpr int ROWS_PER_WAVE   = ROWS_PER_BLOCK / WAVES_PER_BLOCK; // 16
constexpr int GROUPS_PER_WAVE = 4;                                // 16 lanes/row
constexpr int ITERS           = ROWS_PER_WAVE / GROUPS_PER_WAVE;  // 4

constexpr size_t TBL_ELEMS     = (size_t)V_ * N_ * D_;    // 76.8e6 per table
constexpr size_t FP8_TBL_BYTES = TBL_ELEMS;               // 76.8 MB per table
constexpr size_t ACC_BYTES     = 256;
constexpr size_t WS_NEED       = ACC_BYTES + 2 * FP8_TBL_BYTES;

// cvt geometry: one table per launch; 19.2M float4 items; block-tile-contiguous:
// each block owns 1280 consecutive items (256 thr x 5 iters). 15000*1280 exact.
constexpr int CVT_BLOCKS = 15000;
constexpr int CVT_TILE   = 256 * 5;

// Term schedule grouped by negative-sample table slice.
__device__ const int TMAP[15][3] = {
    {0, 0, 0}, {2, 1, 0}, {2, 2, 0},
    {0, 1, 1}, {2, 0, 1}, {2, 2, 1},
    {0, 2, 2}, {2, 0, 2}, {2, 1, 2},
    {1, 1, 0}, {1, 2, 0},
    {1, 0, 1}, {1, 2, 1},
    {1, 0, 2}, {1, 1, 2},
};

typedef float v2f __attribute__((ext_vector_type(2)));
typedef float v4f __attribute__((ext_vector_type(4)));

template <int CTRL>
__device__ __forceinline__ float dpp_add(float v) {
    int x = __builtin_amdgcn_update_dpp(0, __float_as_int(v), CTRL, 0xF, 0xF, true);
    return v + __int_as_float(x);
}

// 16-lane sum on the VALU pipe.
__device__ __forceinline__ float grp_sum16(float v) {
    v = dpp_add<0xB1>(v);
    v = dpp_add<0x4E>(v);
    v = dpp_add<0x124>(v);
    v = dpp_add<0x128>(v);
    return v;
}

__device__ __forceinline__ float log_sigmoid(float x) {
    float ax = fabsf(x);
    return fminf(x, 0.f) - __logf(1.f + __expf(-ax));
}

// ---------------- fp8 e4m3 helpers (HW cvt; selectors constant) ----------------
__device__ __forceinline__ unsigned cvt4_fp8(float a, float b, float c, float d) {
    int v = __builtin_amdgcn_cvt_pk_fp8_f32(a, b, 0, false);
    v = __builtin_amdgcn_cvt_pk_fp8_f32(c, d, v, true);
    return (unsigned)v;
}
template <bool HI>
__device__ __forceinline__ v2f upk2(unsigned v) {
    return __builtin_amdgcn_cvt_pk_f32_fp8((int)v, HI);
}

// Per-table conversion: ONE read stream + ONE write stream per wave
// (split beats fused: round-5/8 evidence — fused doubles the DRAM page
// working set and drops to 4.1 TB/s). Block-tile-contiguous, 5-deep
// forced batch before sched_barrier(0), NT loads (read-once).
template <bool ZERO_ACC>
__global__ __launch_bounds__(256) void cvt_fp8_one(
    const v4f* __restrict__ src, unsigned* __restrict__ dst,
    float* __restrict__ acc)
{
    if (ZERO_ACC && blockIdx.x == 0 && threadIdx.x < 8) acc[threadIdx.x] = 0.f;
    const size_t base = (size_t)blockIdx.x * CVT_TILE + threadIdx.x;

    v4f v0, v1, v2, v3, v4;
    v0 = __builtin_nontemporal_load(&src[base + 0 * 256]);
    v1 = __builtin_nontemporal_load(&src[base + 1 * 256]);
    v2 = __builtin_nontemporal_load(&src[base + 2 * 256]);
    v3 = __builtin_nontemporal_load(&src[base + 3 * 256]);
    v4 = __builtin_nontemporal_load(&src[base + 4 * 256]);
    __builtin_amdgcn_sched_barrier(0);

    dst[base + 0 * 256] = cvt4_fp8(v0.x, v0.y, v0.z, v0.w);
    dst[base + 1 * 256] = cvt4_fp8(v1.x, v1.y, v1.z, v1.w);
    dst[base + 2 * 256] = cvt4_fp8(v2.x, v2.y, v2.z, v2.w);
    dst[base + 3 * 256] = cvt4_fp8(v3.x, v3.y, v3.z, v3.w);
    dst[base + 4 * 256] = cvt4_fp8(v4.x, v4.y, v4.z, v4.w);
}

// dot of this lane's 8 fp8 elements against pre-decoded center (4 x v2f),
// using packed f32 math (v_pk_fma_f32).
__device__ __forceinline__ float dotv(v2f c0, v2f c1, v2f c2, v2f c3, uint2 n) {
    v2f a0 = c0 * upk2<false>(n.x);
    v2f a1 = c1 * upk2<true>(n.x);
    a0 += c2 * upk2<false>(n.y);
    a1 += c3 * upk2<true>(n.y);
    v2f a = a0 + a1;
    return a.x + a.y;
}

// ---------------- fp8 gather kernel ----------------
__global__ __launch_bounds__(256) void sgns_fp8(
    const int*   __restrict__ countp,
    const int*   __restrict__ shuffle,
    const int*   __restrict__ nodes_idx,
    const int*   __restrict__ neigh_idx,
    const int*   __restrict__ neg1,
    const int*   __restrict__ neg2,
    const int*   __restrict__ neg3,
    const uint2* __restrict__ nodeT,
    const uint2* __restrict__ neighT,
    float*       __restrict__ acc)
{
    const int slot = blockIdx.x / BLOCKS_PER_TERM;
    const int blk  = blockIdx.x % BLOCKS_PER_TERM;
    const int wave = threadIdx.x >> 6;
    const int lane = threadIdx.x & 63;
    const int grp  = lane >> 4;
    const int lw   = lane & 15;
    const int count = countp[0];

    const int type = TMAP[slot][0];
    const int i    = TMAP[slot][1];
    const int j    = TMAP[slot][2];

    const int*   negBase;
    const uint2* negTable;
    if (type == 0)      { negTable = neighT + (size_t)i * N_ * 16; negBase = neg1 + (size_t)i * B_ * K_; }
    else if (type == 1) { negTable = nodeT  + (size_t)j * N_ * 16; negBase = neg2 + (size_t)(j * V_ + i) * B_ * K_; }
    else                { negTable = neighT + (size_t)j * N_ * 16; negBase = neg3 + (size_t)(j * V_ + i) * B_ * K_; }

    float wsum = 0.f;
    const int rowbase = blk * ROWS_PER_BLOCK + wave * ROWS_PER_WAVE;

    for (int r = 0; r < ITERS; ++r) {
        const int b  = rowbase + r * GROUPS_PER_WAVE + grp;
        const int sh = shuffle[i * TOT_ + count + b];
        const int ns = nodes_idx[i * TOT_ + sh];

        uint2 c8 = nodeT[((size_t)i * N_ + ns) * 16 + lw];

        const uint2* xrow;
        if (type == 0) {
            int gs = neigh_idx[i * TOT_ + sh];
            xrow = neighT + ((size_t)i * N_ + gs) * 16;
        } else if (type == 1) {
            xrow = nodeT + ((size_t)j * N_ + ns) * 16;
        } else {
            int gs = neigh_idx[i * TOT_ + sh];
            xrow = neighT + ((size_t)j * N_ + gs) * 16;
        }
        uint2 x8 = xrow[lw];

        int myidx = (lw < K_) ? negBase[(size_t)b * K_ + lw] : 0;

        // Broadcast neg indices, then issue ALL 10 neg loads before reducing (MLP).
        uint2 nv[K_];
#pragma unroll
        for (int k = 0; k < K_; ++k) {
            int nk = __shfl(myidx, (lane & 48) | k, 64);
            nv[k] = negTable[(size_t)nk * 16 + lw];
        }

        v2f c0 = upk2<false>(c8.x), c1 = upk2<true>(c8.x);
        v2f c2 = upk2<false>(c8.y), c3 = upk2<true>(c8.y);

        float rowacc = log_sigmoid(grp_sum16(dotv(c0, c1, c2, c3, x8)));
#pragma unroll
        for (int k = 0; k < K_; ++k) {
            rowacc += log_sigmoid(-grp_sum16(dotv(c0, c1, c2, c3, nv[k])));
        }
        wsum += rowacc;
    }

    wsum += __shfl_xor(wsum, 16, 64);
    wsum += __shfl_xor(wsum, 32, 64);

    __shared__ float part[WAVES_PER_BLOCK];
    if (lane == 0) part[wave] = wsum;
    __syncthreads();
    if (threadIdx.x == 0) {
        float s = part[0] + part[1] + part[2] + part[3];
        atomicAdd(&acc[type], s);
    }
}

// ---------------- f32 fallback (proven round-3 kernel) ----------------
__device__ __forceinline__ float dot8(float4 a0, float4 a1, float4 b0, float4 b1) {
    float s = a0.x * b0.x;
    s = fmaf(a0.y, b0.y, s);
    s = fmaf(a0.z, b0.z, s);
    s = fmaf(a0.w, b0.w, s);
    s = fmaf(a1.x, b1.x, s);
    s = fmaf(a1.y, b1.y, s);
    s = fmaf(a1.z, b1.z, s);
    s = fmaf(a1.w, b1.w, s);
    return s;
}

__global__ __launch_bounds__(256) void sgns_f32(
    const int*   __restrict__ countp,
    const int*   __restrict__ shuffle,
    const int*   __restrict__ nodes_idx,
    const int*   __restrict__ neigh_idx,
    const int*   __restrict__ neg1,
    const int*   __restrict__ neg2,
    const int*   __restrict__ neg3,
    const float* __restrict__ node_W,
    const float* __restrict__ neigh_W,
    float*       __restrict__ acc)
{
    const int slot = blockIdx.x / BLOCKS_PER_TERM;
    const int blk  = blockIdx.x % BLOCKS_PER_TERM;
    const int wave = threadIdx.x >> 6;
    const int lane = threadIdx.x & 63;
    const int grp  = lane >> 4;
    const int lw   = lane & 15;
    const int count = countp[0];

    const int type = TMAP[slot][0];
    const int i    = TMAP[slot][1];
    const int j    = TMAP[slot][2];

    const int*   negBase;
    const float* negTable;
    if (type == 0)      { negTable = neigh_W + (size_t)i * N_ * D_; negBase = neg1 + (size_t)i * B_ * K_; }
    else if (type == 1) { negTable = node_W  + (size_t)j * N_ * D_; negBase = neg2 + (size_t)(j * V_ + i) * B_ * K_; }
    else                { negTable = neigh_W + (size_t)j * N_ * D_; negBase = neg3 + (size_t)(j * V_ + i) * B_ * K_; }

    float wsum = 0.f;
    const int rowbase = blk * ROWS_PER_BLOCK + wave * ROWS_PER_WAVE;

    for (int r = 0; r < ITERS; ++r) {
        const int b  = rowbase + r * GROUPS_PER_WAVE + grp;
        const int sh = shuffle[i * TOT_ + count + b];
        const int ns = nodes_idx[i * TOT_ + sh];

        const float* crow = node_W + ((size_t)i * N_ + ns) * (size_t)D_;
        float4 c0 = *(const float4*)(crow + lw * 4);
        float4 c1 = *(const float4*)(crow + 64 + lw * 4);

        const float* xrow;
        if (type == 0) {
            int gs = neigh_idx[i * TOT_ + sh];
            xrow = neigh_W + ((size_t)i * N_ + gs) * (size_t)D_;
        } else if (type == 1) {
            xrow = node_W + ((size_t)j * N_ + ns) * (size_t)D_;
        } else {
            int gs = neigh_idx[i * TOT_ + sh];
            xrow = neigh_W + ((size_t)j * N_ + gs) * (size_t)D_;
        }
        float4 x0 = *(const float4*)(xrow + lw * 4);
        float4 x1 = *(const float4*)(xrow + 64 + lw * 4);

        int myidx = (lw < K_) ? negBase[(size_t)b * K_ + lw] : 0;

        float rowacc = log_sigmoid(grp_sum16(dot8(c0, c1, x0, x1)));
#pragma unroll
        for (int k = 0; k < K_; ++k) {
            int nk = __shfl(myidx, (lane & 48) | k, 64);
            const float* nrow = negTable + (size_t)nk * (size_t)D_;
            float4 n0 = *(const float4*)(nrow + lw * 4);
            float4 n1 = *(const float4*)(nrow + 64 + lw * 4);
            rowacc += log_sigmoid(-grp_sum16(dot8(c0, c1, n0, n1)));
        }
        wsum += rowacc;
    }

    wsum += __shfl_xor(wsum, 16, 64);
    wsum += __shfl_xor(wsum, 32, 64);

    __shared__ float part[WAVES_PER_BLOCK];
    if (lane == 0) part[wave] = wsum;
    __syncthreads();
    if (threadIdx.x == 0) {
        float s = part[0] + part[1] + part[2] + part[3];
        atomicAdd(&acc[type], s);
    }
}

__global__ void finalize_kernel(const float* __restrict__ acc,
                                const float* __restrict__ hyp1,
                                const float* __restrict__ hyp2,
                                float* __restrict__ out)
{
    const float invB = 1.0f / (float)B_;
    float s1 = acc[0], s2 = acc[1], s3 = acc[2];
    out[0] = -(s1 * (invB / 9.0f) + hyp1[0] * s2 * (invB / 18.0f) + hyp2[0] * s3 * (invB / 18.0f));
}

extern "C" void kernel_launch(void* const* d_in, const int* in_sizes, int n_in,
                              void* d_out, int out_size, void* d_ws, size_t ws_size,
                              hipStream_t stream)
{
    const int*   countp    = (const int*)d_in[0];
    const int*   shuffle   = (const int*)d_in[1];
    const int*   nodes_idx = (const int*)d_in[2];
    const int*   neigh_idx = (const int*)d_in[3];
    const int*   neg1      = (const int*)d_in[4];
    const int*   neg2      = (const int*)d_in[5];
    const int*   neg3      = (const int*)d_in[6];
    const float* node_W    = (const float*)d_in[7];
    const float* neigh_W   = (const float*)d_in[8];
    const float* hyp1      = (const float*)d_in[9];
    const float* hyp2      = (const float*)d_in[10];

    float* acc = (float*)d_ws;
    dim3 block(256);

    if (ws_size >= WS_NEED) {
        unsigned* nodeT  = (unsigned*)((char*)d_ws + ACC_BYTES);
        unsigned* neighT = (unsigned*)((char*)d_ws + ACC_BYTES + FP8_TBL_BYTES);
        cvt_fp8_one<true ><<<CVT_BLOCKS, block, 0, stream>>>((const v4f*)node_W,  nodeT,  acc);
        cvt_fp8_one<false><<<CVT_BLOCKS, block, 0, stream>>>((const v4f*)neigh_W, neighT, acc);
        sgns_fp8<<<dim3(15 * BLOCKS_PER_TERM), block, 0, stream>>>(
            countp, shuffle, nodes_idx, neigh_idx, neg1, neg2, neg3,
            (const uint2*)nodeT, (const uint2*)neighT, acc);
    } else {
        (void)hipMemsetAsync(acc, 0, 3 * sizeof(float), stream);
        sgns_f32<<<dim3(15 * BLOCKS_PER_TERM), block, 0, stream>>>(
            countp, shuffle, nodes_idx, neigh_idx, neg1, neg2, neg3,
            node_W, neigh_W, acc);
    }

    finalize_kernel<<<1, 1, 0, stream>>>(acc, hyp1, hyp2, (float*)d_out);
}